// Round 2
// baseline (516.236 us; speedup 1.0000x reference)
//
#include <hip/hip_runtime.h>
#include <hip/hip_bf16.h>
#include <hip/hip_cooperative_groups.h>

namespace cg = cooperative_groups;

// ---------------------------------------------------------------------------
// GHN (float32 I/O), fused single cooperative kernel:
//   phase1 encode (3 gathered GEMMs, bf16 MFMA, f32 acc) + dinv
//   phase2 z1    (partial-reduce + feats@W1, dinv-scaled)
//   phase3 prop  (An @ Z1s, relu, @W2)      [mode 0]
//   phase4 prop  (An @ Z2s -> bf16 Xb)      [mode 1]
//   phase5 decode (gathered GEMMs, MFMA) -> f32 out
// Phases separated by grid.sync() instead of kernel re-launches.
// Legacy 5-kernel path retained as fallback if cooperative launch fails.
// ---------------------------------------------------------------------------

typedef __attribute__((ext_vector_type(8))) __bf16 bf16x8;
typedef __attribute__((ext_vector_type(4))) float f32x4;

#define MFMA16(a,b,c) __builtin_amdgcn_mfma_f32_16x16x32_bf16((a),(b),(c),0,0,0)

__device__ __forceinline__ bf16x8 cvt8(const float* p) {
    float4 a = *(const float4*)p;
    float4 b = *(const float4*)(p + 4);
    bf16x8 r;
    r[0]=(__bf16)a.x; r[1]=(__bf16)a.y; r[2]=(__bf16)a.z; r[3]=(__bf16)a.w;
    r[4]=(__bf16)b.x; r[5]=(__bf16)b.y; r[6]=(__bf16)b.z; r[7]=(__bf16)b.w;
    return r;
}

template<int KSTEPS, int DIV>
__device__ __forceinline__ void enc_tile(const float* Ar,
                                         const float* B0,
                                         const float* B1,
                                         int kw, int kg, f32x4& acc0, f32x4& acc1)
{
#pragma unroll
    for (int s = 0; s < KSTEPS; ++s) {
        int k = kw + s*32 + kg*8;
        int col = DIV ? (k + (k/DIV)*DIV) : k;   // gathered (padded) column
        bf16x8 a  = cvt8(Ar + k);
        bf16x8 b0 = cvt8(B0 + col);
        bf16x8 b1 = cvt8(B1 + col);
        acc0 = MFMA16(a, b0, acc0);
        acc1 = MFMA16(a, b1, acc1);
    }
}

struct GhnP {
    const float *conv_w, *lin_w, *bias_w;
    const float *conv_enc_w, *lin_enc_w, *bias_enc_w;
    const float *conv_enc_b, *lin_enc_b, *bias_enc_b;
    const float *gcn_w1, *gcn_w2;
    const float *cW, *cB, *lW, *lB, *bW, *bB;
    const float *embed_tab;
    const int   *adj, *prims;
    float *P, *Z1s, *Z2s, *dinv;
    unsigned short *Xb;
    float *out;
};

// ---------------------------------------------------------------------------
// prop unit (shared by phase 3 and 4); smem: adjf[4*1025], red[4*96]
// ---------------------------------------------------------------------------
__device__ __forceinline__ void prop_unit(const GhnP& gp, const float* Zs,
                                          float* adjf, float* red,
                                          int blk, int tid, int mode)
{
    int i0 = blk * 4;
    int nr = (1025 - i0 < 4) ? (1025 - i0) : 4;
    for (int idx = tid; idx < nr*1025; idx += 256)
        adjf[idx] = (float)gp.adj[(size_t)i0*1025 + idx];
    for (int idx = nr*1025 + tid; idx < 4*1025; idx += 256)
        adjf[idx] = 0.f;                                 // tail
    red[tid] = 0.f; if (tid < 128) red[256+tid] = 0.f;
    __syncthreads();
    if (tid < nr) adjf[tid*1025 + i0 + tid] += 1.0f;     // + identity
    __syncthreads();

    if (tid < 240) {
        int c4 = tid % 24, jg = tid / 24;
        float acc[4][4] = {};
        for (int j = jg; j < 1025; j += 10) {
            const float4 z = *(const float4*)(Zs + (size_t)j*96 + c4*4);
#pragma unroll
            for (int r = 0; r < 4; ++r) {
                float av = adjf[r*1025 + j];
                acc[r][0] += av*z.x; acc[r][1] += av*z.y;
                acc[r][2] += av*z.z; acc[r][3] += av*z.w;
            }
        }
#pragma unroll
        for (int r = 0; r < 4; ++r) {
            atomicAdd(&red[r*96 + c4*4 + 0], acc[r][0]);
            atomicAdd(&red[r*96 + c4*4 + 1], acc[r][1]);
            atomicAdd(&red[r*96 + c4*4 + 2], acc[r][2]);
            atomicAdd(&red[r*96 + c4*4 + 3], acc[r][3]);
        }
    }
    __syncthreads();

    if (mode == 0) {
        if (tid < 96) {
            int rl = tid / 24, c4 = tid % 24;
            int i = i0 + rl;
            if (rl < nr) {
                float di = gp.dinv[i];
                float o0=0,o1=0,o2=0,o3=0;
                for (int c = 0; c < 96; ++c) {
                    float hv = red[rl*96+c]*di; hv = hv > 0.f ? hv : 0.f;
                    float4 w2 = *(const float4*)(gp.gcn_w2 + c*96 + c4*4);
                    o0 += hv*w2.x; o1 += hv*w2.y; o2 += hv*w2.z; o3 += hv*w2.w;
                }
                float* o = gp.Z2s + (size_t)i*96 + c4*4;
                o[0] = di*o0; o[1] = di*o1; o[2] = di*o2; o[3] = di*o3;
            }
        }
    } else {
        for (int idx = tid; idx < nr*96; idx += 256) {
            int rl = idx / 96, c = idx % 96;
            int i = i0 + rl;
            __hip_bfloat16 hb = __float2bfloat16(gp.dinv[i]*red[rl*96+c]);
            gp.Xb[(size_t)i*96 + c] = *(unsigned short*)&hb;
        }
    }
    __syncthreads();   // WAR: next unit rewrites adjf/red
}

// ---------------------------------------------------------------------------
__global__ __launch_bounds__(256) void k_fused(GhnP gp)
{
    __shared__ float smem[4*1025 + 4*96];   // 17.9 KB (prop); aliased by enc/z1
    const int tid = threadIdx.x;
    const int w = tid >> 6, lane = tid & 63;
    const int n16 = lane & 15, kg = lane >> 4;
    cg::grid_group grid = cg::this_grid();

    // ---------------- phase 1: encoder partials + dinv ----------------
    for (int b = blockIdx.x; b < 656; b += gridDim.x) {
        if (b >= 592) {  // dinv[i] = 1/sqrt(1 + sum_j adj[i][j])
            int wid = (b - 592)*4 + w;
            for (int r = wid; r < 1025; r += 256) {
                const int* row = gp.adj + (size_t)r*1025;
                int s = 0;
#pragma unroll
                for (int i = 0; i <= 16; ++i) {
                    int j = lane + i*64;
                    if (j < 1025) s += row[j];
                }
#pragma unroll
                for (int off = 32; off; off >>= 1) s += __shfl_xor(s, off, 64);
                if (lane == 0) gp.dinv[r] = 1.0f / sqrtf((float)s + 1.0f);
            }
            continue;
        }

        f32x4 acc0 = {0.f,0.f,0.f,0.f}, acc1 = {0.f,0.f,0.f,0.f};
        int slot, nodebase, mtile;
        if (b < 512) {            // conv encoder: M=512, K=36864, 16 ks x 4 w
            mtile = b >> 4; int ks = b & 15;
            slot = ks; nodebase = 0;
            const float* Ar = gp.conv_w     + (size_t)(mtile*16 + n16)*36864;
            const float* B0 = gp.conv_enc_w + (size_t)n16*147456;
            const float* B1 = gp.conv_enc_w + (size_t)(16+n16)*147456;
            enc_tile<18,576>(Ar, B0, B1, ks*2304 + w*576, kg, acc0, acc1);
        } else if (b < 576) {     // lin encoder: M=256, K=4096, 4 ks x 4 w
            int bb = b - 512; mtile = bb >> 2; int ks = bb & 3;
            slot = ks; nodebase = 512;
            const float* Ar = gp.lin_w     + (size_t)(mtile*16 + n16)*4096;
            const float* B0 = gp.lin_enc_w + (size_t)n16*16384;
            const float* B1 = gp.lin_enc_w + (size_t)(16+n16)*16384;
            enc_tile<8,64>(Ar, B0, B1, ks*1024 + w*256, kg, acc0, acc1);
        } else {                  // bias encoder: M=256, K=64 (waves 2,3 idle)
            mtile = b - 576; slot = 0; nodebase = 768;
            if (w < 2) {
                const float* Ar = gp.bias_w     + (size_t)(mtile*16 + n16)*64;
                const float* B0 = gp.bias_enc_w + (size_t)n16*128;
                const float* B1 = gp.bias_enc_w + (size_t)(16+n16)*128;
                enc_tile<1,0>(Ar, B0, B1, w*32, kg, acc0, acc1);
            }
        }

        float* R = smem;          // 4*16*32 = 2048 floats
#pragma unroll
        for (int r = 0; r < 4; ++r) {
            R[(w*16 + kg*4 + r)*32 + n16]      = acc0[r];
            R[(w*16 + kg*4 + r)*32 + 16 + n16] = acc1[r];
        }
        __syncthreads();
        for (int e = tid; e < 512; e += 256) {
            float s = R[e] + R[512+e] + R[1024+e] + R[1536+e];
            int nl = e >> 5, h = e & 31;
            int node = nodebase + mtile*16 + nl;
            gp.P[((size_t)slot*1024 + node)*32 + h] = s;
        }
        __syncthreads();          // WAR: next unit rewrites R
    }
    grid.sync();

    // ---------------- phase 2: z1 ----------------
    for (int blk = blockIdx.x; blk < 129; blk += gridDim.x) {
        float* El = smem;         // 8*32
        float* Ml = smem + 256;   // 8*32
        int i0 = blk * 8;
        {
            int rl = tid >> 5, h = tid & 31;
            int i = i0 + rl;
            if (i < 1025) {
                float e, m;
                if (i == 0) { e = 1.0f; m = 1.0f; }
                else {
                    int node = i - 1;
                    int ns; float bias;
                    if (node < 512)      { ns = 16; bias = gp.conv_enc_b[h]; }
                    else if (node < 768) { ns = 4;  bias = gp.lin_enc_b[h];  }
                    else                 { ns = 1;  bias = gp.bias_enc_b[h]; }
                    float s = bias;
                    for (int sl = 0; sl < ns; ++sl)
                        s += gp.P[((size_t)sl*1024 + node)*32 + h];
                    e = s;
                    m = gp.embed_tab[gp.prims[node]*32 + h];
                }
                El[rl*32+h] = e; Ml[rl*32+h] = m;
            }
        }
        __syncthreads();
        if (tid < 192) {
            int rl = tid / 24, c4 = tid % 24;
            int i = i0 + rl;
            if (i < 1025) {
                float a0=0,a1=0,a2=0,a3=0;
                for (int h = 0; h < 32; ++h) {
                    float e = El[rl*32+h], m = Ml[rl*32+h];
                    float4 wa = *(const float4*)(gp.gcn_w1 + h*96 + c4*4);
                    float4 wb = *(const float4*)(gp.gcn_w1 + (h+32)*96 + c4*4);
                    float4 wc = *(const float4*)(gp.gcn_w1 + (h+64)*96 + c4*4);
                    a0 += e*(wa.x+wb.x) + m*wc.x;
                    a1 += e*(wa.y+wb.y) + m*wc.y;
                    a2 += e*(wa.z+wb.z) + m*wc.z;
                    a3 += e*(wa.w+wb.w) + m*wc.w;
                }
                float di = gp.dinv[i];
                float* o = gp.Z1s + (size_t)i*96 + c4*4;
                o[0] = di*a0; o[1] = di*a1; o[2] = di*a2; o[3] = di*a3;
            }
        }
        __syncthreads();
    }
    grid.sync();

    // ---------------- phase 3: prop mode 0 (Z1s -> Z2s) ----------------
    {
        float* adjf = smem;
        float* red  = smem + 4*1025;
        for (int blk = blockIdx.x; blk < 257; blk += gridDim.x)
            prop_unit(gp, gp.Z1s, adjf, red, blk, tid, 0);
    }
    grid.sync();

    // ---------------- phase 4: prop mode 1 (Z2s -> Xb) ----------------
    {
        float* adjf = smem;
        float* red  = smem + 4*1025;
        for (int blk = blockIdx.x; blk < 257; blk += gridDim.x)
            prop_unit(gp, gp.Z2s, adjf, red, blk, tid, 1);
    }
    grid.sync();

    // ---------------- phase 5: decode ----------------
    for (int b = blockIdx.x; b < 609; b += gridDim.x) {
        const float *W, *Bv;
        int g0, kcw, ncols, div, ostride;
        size_t obase;
        if (b < 576) {                       // conv decoder
            int kb = b >> 1, mb = b & 1;
            W = gp.cW; Bv = gp.cB; g0 = 1 + mb*256; kcw = kb*128 + w*32;
            ncols = 36864; div = 576;
            obase = (size_t)mb*256*36864; ostride = 36864;
        } else if (b < 608) {                // lin decoder
            int kb = b - 576;
            W = gp.lW; Bv = gp.lB; g0 = 513; kcw = kb*128 + w*32;
            ncols = 4096; div = 64; obase = (size_t)18874368; ostride = 4096;
        } else {                             // bias decoder
            W = gp.bW; Bv = gp.bB; g0 = 769; kcw = w*32;
            ncols = 64; div = 0; obase = (size_t)19922944; ostride = 64;
        }
        if (kcw < ncols) {
            int kc_a = kcw + n16, kc_b = kcw + 16 + n16;
            int row_a = div ? kc_a + (kc_a/div)*div : kc_a;
            int row_b = div ? kc_b + (kc_b/div)*div : kc_b;
            const float* Wa = W + (size_t)row_a*96 + kg*8;
            const float* Wb = W + (size_t)row_b*96 + kg*8;
            bf16x8 ba0 = cvt8(Wa);
            bf16x8 ba1 = cvt8(Wa + 32);
            bf16x8 ba2 = cvt8(Wa + 64);
            bf16x8 bb0 = cvt8(Wb);
            bf16x8 bb1 = cvt8(Wb + 32);
            bf16x8 bb2 = cvt8(Wb + 64);
            float bva = Bv[row_a], bvb = Bv[row_b];

#pragma unroll 2
            for (int mt = 0; mt < 16; ++mt) {
                const unsigned short* Ar =
                    gp.Xb + (size_t)(g0 + mt*16 + n16)*96 + kg*8;
                bf16x8 a0 = *(const bf16x8*)(Ar);
                bf16x8 a1 = *(const bf16x8*)(Ar + 32);
                bf16x8 a2 = *(const bf16x8*)(Ar + 64);
                f32x4 acc0 = {0.f,0.f,0.f,0.f}, acc1 = {0.f,0.f,0.f,0.f};
                acc0 = MFMA16(a0, ba0, acc0);
                acc0 = MFMA16(a1, ba1, acc0);
                acc0 = MFMA16(a2, ba2, acc0);
                acc1 = MFMA16(a0, bb0, acc1);
                acc1 = MFMA16(a1, bb1, acc1);
                acc1 = MFMA16(a2, bb2, acc1);
#pragma unroll
                for (int r = 0; r < 4; ++r) {
                    int node = mt*16 + kg*4 + r;
                    gp.out[obase + (size_t)node*ostride + kc_a] = acc0[r] + bva;
                    gp.out[obase + (size_t)node*ostride + kc_b] = acc1[r] + bvb;
                }
            }
        }
    }
}

// ===========================================================================
// Legacy 5-kernel path (fallback if cooperative launch is rejected)
// ===========================================================================
__global__ __launch_bounds__(256) void k_enc(
    const float* __restrict__ conv_w,
    const float* __restrict__ lin_w,
    const float* __restrict__ bias_w,
    const float* __restrict__ conv_enc_w,
    const float* __restrict__ lin_enc_w,
    const float* __restrict__ bias_enc_w,
    const int* __restrict__ adj,
    float* __restrict__ P, float* __restrict__ dinv)
{
    int b = blockIdx.x, tid = threadIdx.x;
    int w = tid >> 6, lane = tid & 63;
    int n16 = lane & 15, kg = lane >> 4;

    if (b >= 592) {
        int wid = (b - 592)*4 + w;
        for (int r = wid; r < 1025; r += 256) {
            const int* row = adj + (size_t)r*1025;
            int s = 0;
#pragma unroll
            for (int i = 0; i <= 16; ++i) {
                int j = lane + i*64;
                if (j < 1025) s += row[j];
            }
#pragma unroll
            for (int off = 32; off; off >>= 1) s += __shfl_xor(s, off, 64);
            if (lane == 0) dinv[r] = 1.0f / sqrtf((float)s + 1.0f);
        }
        return;
    }

    f32x4 acc0 = {0.f,0.f,0.f,0.f}, acc1 = {0.f,0.f,0.f,0.f};
    int slot, nodebase, mtile;
    if (b < 512) {
        mtile = b >> 4; int ks = b & 15;
        slot = ks; nodebase = 0;
        const float* Ar = conv_w     + (size_t)(mtile*16 + n16)*36864;
        const float* B0 = conv_enc_w + (size_t)n16*147456;
        const float* B1 = conv_enc_w + (size_t)(16+n16)*147456;
        enc_tile<18,576>(Ar, B0, B1, ks*2304 + w*576, kg, acc0, acc1);
    } else if (b < 576) {
        int bb = b - 512; mtile = bb >> 2; int ks = bb & 3;
        slot = ks; nodebase = 512;
        const float* Ar = lin_w     + (size_t)(mtile*16 + n16)*4096;
        const float* B0 = lin_enc_w + (size_t)n16*16384;
        const float* B1 = lin_enc_w + (size_t)(16+n16)*16384;
        enc_tile<8,64>(Ar, B0, B1, ks*1024 + w*256, kg, acc0, acc1);
    } else {
        mtile = b - 576; slot = 0; nodebase = 768;
        if (w < 2) {
            const float* Ar = bias_w     + (size_t)(mtile*16 + n16)*64;
            const float* B0 = bias_enc_w + (size_t)n16*128;
            const float* B1 = bias_enc_w + (size_t)(16+n16)*128;
            enc_tile<1,0>(Ar, B0, B1, w*32, kg, acc0, acc1);
        }
    }

    __shared__ float R[4*16*32];
#pragma unroll
    for (int r = 0; r < 4; ++r) {
        R[(w*16 + kg*4 + r)*32 + n16]      = acc0[r];
        R[(w*16 + kg*4 + r)*32 + 16 + n16] = acc1[r];
    }
    __syncthreads();
    for (int e = tid; e < 512; e += 256) {
        float s = R[e] + R[512+e] + R[1024+e] + R[1536+e];
        int nl = e >> 5, h = e & 31;
        int node = nodebase + mtile*16 + nl;
        P[((size_t)slot*1024 + node)*32 + h] = s;
    }
}

__global__ __launch_bounds__(256) void k_z1(
    const float* __restrict__ P,
    const float* __restrict__ conv_enc_b,
    const float* __restrict__ lin_enc_b,
    const float* __restrict__ bias_enc_b,
    const float* __restrict__ embed_tab,
    const int* __restrict__ prims,
    const float* __restrict__ gcn_w1,
    const float* __restrict__ dinv,
    float* __restrict__ Z1s)
{
    __shared__ float El[8*32], Ml[8*32];
    int tid = threadIdx.x;
    int i0 = blockIdx.x * 8;
    {
        int rl = tid >> 5, h = tid & 31;
        int i = i0 + rl;
        if (i < 1025) {
            float e, m;
            if (i == 0) { e = 1.0f; m = 1.0f; }
            else {
                int node = i - 1;
                int ns; float bias;
                if (node < 512)      { ns = 16; bias = conv_enc_b[h]; }
                else if (node < 768) { ns = 4;  bias = lin_enc_b[h];  }
                else                 { ns = 1;  bias = bias_enc_b[h]; }
                float s = bias;
                for (int sl = 0; sl < ns; ++sl)
                    s += P[((size_t)sl*1024 + node)*32 + h];
                e = s;
                m = embed_tab[prims[node]*32 + h];
            }
            El[rl*32+h] = e; Ml[rl*32+h] = m;
        }
    }
    __syncthreads();
    if (tid < 192) {
        int rl = tid / 24, c4 = tid % 24;
        int i = i0 + rl;
        if (i < 1025) {
            float a0=0,a1=0,a2=0,a3=0;
            for (int h = 0; h < 32; ++h) {
                float e = El[rl*32+h], m = Ml[rl*32+h];
                float4 wa = *(const float4*)(gcn_w1 + h*96 + c4*4);
                float4 wb = *(const float4*)(gcn_w1 + (h+32)*96 + c4*4);
                float4 wc = *(const float4*)(gcn_w1 + (h+64)*96 + c4*4);
                a0 += e*(wa.x+wb.x) + m*wc.x;
                a1 += e*(wa.y+wb.y) + m*wc.y;
                a2 += e*(wa.z+wb.z) + m*wc.z;
                a3 += e*(wa.w+wb.w) + m*wc.w;
            }
            float di = dinv[i];
            float* o = Z1s + (size_t)i*96 + c4*4;
            o[0] = di*a0; o[1] = di*a1; o[2] = di*a2; o[3] = di*a3;
        }
    }
}

__global__ __launch_bounds__(256) void k_prop(
    const float* __restrict__ Zs, const int* __restrict__ adj,
    const float* __restrict__ dinv, const float* __restrict__ gcn_w2,
    float* __restrict__ Zout, unsigned short* __restrict__ Xb, int mode)
{
    __shared__ float adjf[4*1025];
    __shared__ float red[4*96];
    int tid = threadIdx.x;
    int i0 = blockIdx.x * 4;
    int nr = (1025 - i0 < 4) ? (1025 - i0) : 4;
    for (int idx = tid; idx < nr*1025; idx += 256)
        adjf[idx] = (float)adj[(size_t)i0*1025 + idx];
    for (int idx = nr*1025 + tid; idx < 4*1025; idx += 256)
        adjf[idx] = 0.f;
    red[tid] = 0.f; if (tid < 128) red[256+tid] = 0.f;
    __syncthreads();
    if (tid < nr) adjf[tid*1025 + i0 + tid] += 1.0f;
    __syncthreads();

    if (tid < 240) {
        int c4 = tid % 24, jg = tid / 24;
        float acc[4][4] = {};
        for (int j = jg; j < 1025; j += 10) {
            const float4 z = *(const float4*)(Zs + (size_t)j*96 + c4*4);
#pragma unroll
            for (int r = 0; r < 4; ++r) {
                float av = adjf[r*1025 + j];
                acc[r][0] += av*z.x; acc[r][1] += av*z.y;
                acc[r][2] += av*z.z; acc[r][3] += av*z.w;
            }
        }
#pragma unroll
        for (int r = 0; r < 4; ++r) {
            atomicAdd(&red[r*96 + c4*4 + 0], acc[r][0]);
            atomicAdd(&red[r*96 + c4*4 + 1], acc[r][1]);
            atomicAdd(&red[r*96 + c4*4 + 2], acc[r][2]);
            atomicAdd(&red[r*96 + c4*4 + 3], acc[r][3]);
        }
    }
    __syncthreads();

    if (mode == 0) {
        if (tid < 96) {
            int rl = tid / 24, c4 = tid % 24;
            int i = i0 + rl;
            if (rl < nr) {
                float di = dinv[i];
                float o0=0,o1=0,o2=0,o3=0;
                for (int c = 0; c < 96; ++c) {
                    float hv = red[rl*96+c]*di; hv = hv > 0.f ? hv : 0.f;
                    float4 w2 = *(const float4*)(gcn_w2 + c*96 + c4*4);
                    o0 += hv*w2.x; o1 += hv*w2.y; o2 += hv*w2.z; o3 += hv*w2.w;
                }
                float* o = Zout + (size_t)i*96 + c4*4;
                o[0] = di*o0; o[1] = di*o1; o[2] = di*o2; o[3] = di*o3;
            }
        }
    } else {
        for (int idx = tid; idx < nr*96; idx += 256) {
            int rl = idx / 96, c = idx % 96;
            int i = i0 + rl;
            __hip_bfloat16 hb = __float2bfloat16(dinv[i]*red[rl*96+c]);
            Xb[(size_t)i*96 + c] = *(unsigned short*)&hb;
        }
    }
}

__global__ __launch_bounds__(256) void k_dec(
    const unsigned short* __restrict__ Xb,
    const float* __restrict__ cW, const float* __restrict__ cB,
    const float* __restrict__ lW, const float* __restrict__ lB,
    const float* __restrict__ bW, const float* __restrict__ bB,
    float* __restrict__ out)
{
    int b = blockIdx.x, tid = threadIdx.x;
    int w = tid >> 6, lane = tid & 63;
    int n16 = lane & 15, kg = lane >> 4;

    const float *W, *Bv;
    int g0, kcw, ncols, div, ostride;
    size_t obase;
    if (b < 576) {
        int kb = b >> 1, mb = b & 1;
        W = cW; Bv = cB; g0 = 1 + mb*256; kcw = kb*128 + w*32; ncols = 36864;
        div = 576; obase = (size_t)mb*256*36864; ostride = 36864;
    } else if (b < 608) {
        int kb = b - 576;
        W = lW; Bv = lB; g0 = 513; kcw = kb*128 + w*32; ncols = 4096;
        div = 64; obase = (size_t)18874368; ostride = 4096;
    } else {
        W = bW; Bv = bB; g0 = 769; kcw = w*32; ncols = 64;
        div = 0; obase = (size_t)19922944; ostride = 64;
    }
    if (kcw >= ncols) return;

    int kc_a = kcw + n16, kc_b = kcw + 16 + n16;
    int row_a = div ? kc_a + (kc_a/div)*div : kc_a;
    int row_b = div ? kc_b + (kc_b/div)*div : kc_b;
    const float* Wa = W + (size_t)row_a*96 + kg*8;
    const float* Wb = W + (size_t)row_b*96 + kg*8;
    bf16x8 ba0 = cvt8(Wa);
    bf16x8 ba1 = cvt8(Wa + 32);
    bf16x8 ba2 = cvt8(Wa + 64);
    bf16x8 bb0 = cvt8(Wb);
    bf16x8 bb1 = cvt8(Wb + 32);
    bf16x8 bb2 = cvt8(Wb + 64);
    float bva = Bv[row_a], bvb = Bv[row_b];

#pragma unroll 2
    for (int mt = 0; mt < 16; ++mt) {
        const unsigned short* Ar = Xb + (size_t)(g0 + mt*16 + n16)*96 + kg*8;
        bf16x8 a0 = *(const bf16x8*)(Ar);
        bf16x8 a1 = *(const bf16x8*)(Ar + 32);
        bf16x8 a2 = *(const bf16x8*)(Ar + 64);
        f32x4 acc0 = {0.f,0.f,0.f,0.f}, acc1 = {0.f,0.f,0.f,0.f};
        acc0 = MFMA16(a0, ba0, acc0);
        acc0 = MFMA16(a1, ba1, acc0);
        acc0 = MFMA16(a2, ba2, acc0);
        acc1 = MFMA16(a0, bb0, acc1);
        acc1 = MFMA16(a1, bb1, acc1);
        acc1 = MFMA16(a2, bb2, acc1);
#pragma unroll
        for (int r = 0; r < 4; ++r) {
            int node = mt*16 + kg*4 + r;
            out[obase + (size_t)node*ostride + kc_a] = acc0[r] + bva;
            out[obase + (size_t)node*ostride + kc_b] = acc1[r] + bvb;
        }
    }
}

// ---------------------------------------------------------------------------
extern "C" void kernel_launch(void* const* d_in, const int* in_sizes, int n_in,
                              void* d_out, int out_size, void* d_ws, size_t ws_size,
                              hipStream_t stream)
{
    const float* conv_w     = (const float*)d_in[0];
    const float* lin_w      = (const float*)d_in[1];
    const float* bias_w     = (const float*)d_in[2];
    const float* conv_enc_w = (const float*)d_in[3];
    const float* conv_enc_b = (const float*)d_in[4];
    const float* lin_enc_w  = (const float*)d_in[5];
    const float* lin_enc_b  = (const float*)d_in[6];
    const float* bias_enc_w = (const float*)d_in[7];
    const float* bias_enc_b = (const float*)d_in[8];
    const float* gcn_w1     = (const float*)d_in[9];
    const float* gcn_w2     = (const float*)d_in[10];
    const float* conv_dec_w = (const float*)d_in[11];
    const float* conv_dec_b = (const float*)d_in[12];
    const float* lin_dec_w  = (const float*)d_in[13];
    const float* lin_dec_b  = (const float*)d_in[14];
    const float* bias_dec_w = (const float*)d_in[15];
    const float* bias_dec_b = (const float*)d_in[16];
    const float* embed_tab  = (const float*)d_in[17];
    const int*   adj        = (const int*)d_in[18];
    const int*   prims      = (const int*)d_in[19];

    // workspace layout (floats): P 16*1024*32 | Z1s | Z2s | dinv | Xb(bf16)
    float* P    = (float*)d_ws;
    float* Z1s  = P + (size_t)16*1024*32;
    float* Z2s  = Z1s + 1025*96;
    float* dinv = Z2s + 1025*96;
    unsigned short* Xb = (unsigned short*)(dinv + 1056);

    GhnP gp;
    gp.conv_w = conv_w; gp.lin_w = lin_w; gp.bias_w = bias_w;
    gp.conv_enc_w = conv_enc_w; gp.lin_enc_w = lin_enc_w; gp.bias_enc_w = bias_enc_w;
    gp.conv_enc_b = conv_enc_b; gp.lin_enc_b = lin_enc_b; gp.bias_enc_b = bias_enc_b;
    gp.gcn_w1 = gcn_w1; gp.gcn_w2 = gcn_w2;
    gp.cW = conv_dec_w; gp.cB = conv_dec_b;
    gp.lW = lin_dec_w;  gp.lB = lin_dec_b;
    gp.bW = bias_dec_w; gp.bB = bias_dec_b;
    gp.embed_tab = embed_tab; gp.adj = adj; gp.prims = prims;
    gp.P = P; gp.Z1s = Z1s; gp.Z2s = Z2s; gp.dinv = dinv; gp.Xb = Xb;
    gp.out = (float*)d_out;

    // cooperative grid size: 1 or 2 blocks/CU, validated by occupancy query
    static int coop_state = 0;   // 0=unknown, >0=grid blocks, -1=use fallback
    if (coop_state == 0) {
        int nb = 0;
        hipError_t e = hipOccupancyMaxActiveBlocksPerMultiprocessor(
            &nb, k_fused, 256, 0);
        if (e != hipSuccess || nb < 1) coop_state = -1;
        else coop_state = 256 * (nb >= 2 ? 2 : 1);
    }

    bool done = false;
    if (coop_state > 0) {
        void* args[] = { (void*)&gp };
        hipError_t e = hipLaunchCooperativeKernel(
            (void*)k_fused, dim3(coop_state), dim3(256), args, 0, stream);
        if (e == hipSuccess) done = true;
        else { (void)hipGetLastError(); coop_state = -1; }
    }

    if (!done) {   // legacy 5-kernel fallback
        k_enc<<<656, 256, 0, stream>>>(conv_w, lin_w, bias_w,
                                       conv_enc_w, lin_enc_w, bias_enc_w,
                                       adj, P, dinv);
        k_z1<<<129, 256, 0, stream>>>(P, conv_enc_b, lin_enc_b, bias_enc_b,
                                      embed_tab, prims, gcn_w1, dinv, Z1s);
        k_prop<<<257, 256, 0, stream>>>(Z1s, adj, dinv, gcn_w2, Z2s, Xb, 0);
        k_prop<<<257, 256, 0, stream>>>(Z2s, adj, dinv, gcn_w2, Z2s, Xb, 1);
        k_dec<<<609, 256, 0, stream>>>(Xb, conv_dec_w, conv_dec_b,
                                       lin_dec_w, lin_dec_b,
                                       bias_dec_w, bias_dec_b,
                                       (float*)d_out);
    }
}

// Round 3
// 334.744 us; speedup vs baseline: 1.5422x; 1.5422x over previous
//
#include <hip/hip_runtime.h>
#include <hip/hip_bf16.h>

// ---------------------------------------------------------------------------
// GHN (float32 I/O): encode (3 gathered GEMMs, bf16 MFMA, f32 acc)
//   -> 2-layer GCN (pure f32 vector) -> decode (gathered GEMMs, MFMA) -> f32
// Multi-kernel structure (fused coop version regressed: half concurrency).
// This revision raises waves-in-flight in every phase (latency-bound network:
// measured 5% HBM, 0.5% MFMA, 23% occupancy at 358 us fused).
// ---------------------------------------------------------------------------

typedef __attribute__((ext_vector_type(8))) __bf16 bf16x8;
typedef __attribute__((ext_vector_type(4))) float f32x4;

#define MFMA16(a,b,c) __builtin_amdgcn_mfma_f32_16x16x32_bf16((a),(b),(c),0,0,0)

__device__ __forceinline__ bf16x8 cvt8(const float* p) {
    float4 a = *(const float4*)p;
    float4 b = *(const float4*)(p + 4);
    bf16x8 r;
    r[0]=(__bf16)a.x; r[1]=(__bf16)a.y; r[2]=(__bf16)a.z; r[3]=(__bf16)a.w;
    r[4]=(__bf16)b.x; r[5]=(__bf16)b.y; r[6]=(__bf16)b.z; r[7]=(__bf16)b.w;
    return r;
}

template<int KSTEPS, int DIV>
__device__ __forceinline__ void enc_tile(const float* Ar,
                                         const float* B0,
                                         const float* B1,
                                         int kw, int kg, f32x4& acc0, f32x4& acc1)
{
#pragma unroll
    for (int s = 0; s < KSTEPS; ++s) {
        int k = kw + s*32 + kg*8;
        int col = DIV ? (k + (k/DIV)*DIV) : k;   // gathered (padded) column
        bf16x8 a  = cvt8(Ar + k);
        bf16x8 b0 = cvt8(B0 + col);
        bf16x8 b1 = cvt8(B1 + col);
        acc0 = MFMA16(a, b0, acc0);
        acc1 = MFMA16(a, b1, acc1);
    }
}

// ---------------------------------------------------------------------------
// k_enc: 512-thread blocks, 8 waves (was 4) -> 16 waves/CU for latency hiding.
// Same K-slot structure (16 conv slots, 4 lin slots); per-wave chunk halved.
// ---------------------------------------------------------------------------
__global__ __launch_bounds__(512) void k_enc(
    const float* __restrict__ conv_w,
    const float* __restrict__ lin_w,
    const float* __restrict__ bias_w,
    const float* __restrict__ conv_enc_w,
    const float* __restrict__ lin_enc_w,
    const float* __restrict__ bias_enc_w,
    const int* __restrict__ adj,
    float* __restrict__ P, float* __restrict__ dinv)
{
    int b = blockIdx.x, tid = threadIdx.x;
    int w = tid >> 6, lane = tid & 63;      // w in [0,8)
    int n16 = lane & 15, kg = lane >> 4;

    if (b >= 592) {  // ---- dinv: 16 blocks x 8 waves = 128 waves
        int wid = (b - 592)*8 + w;
        for (int r = wid; r < 1025; r += 128) {
            const int* row = adj + (size_t)r*1025;
            int s = 0;
#pragma unroll
            for (int i = 0; i <= 16; ++i) {
                int j = lane + i*64;
                if (j < 1025) s += row[j];
            }
#pragma unroll
            for (int off = 32; off; off >>= 1) s += __shfl_xor(s, off, 64);
            if (lane == 0) dinv[r] = 1.0f / sqrtf((float)s + 1.0f);
        }
        return;
    }

    f32x4 acc0 = {0.f,0.f,0.f,0.f}, acc1 = {0.f,0.f,0.f,0.f};
    int slot, nodebase, mtile;
    if (b < 512) {            // conv encoder: M=512, K=36864, 16 ks x 8 waves
        mtile = b >> 4; int ks = b & 15;
        slot = ks; nodebase = 0;
        const float* Ar = conv_w     + (size_t)(mtile*16 + n16)*36864;
        const float* B0 = conv_enc_w + (size_t)n16*147456;
        const float* B1 = conv_enc_w + (size_t)(16+n16)*147456;
        enc_tile<9,576>(Ar, B0, B1, ks*2304 + w*288, kg, acc0, acc1);
    } else if (b < 576) {     // lin encoder: M=256, K=4096, 4 ks x 8 waves
        int bb = b - 512; mtile = bb >> 2; int ks = bb & 3;
        slot = ks; nodebase = 512;
        const float* Ar = lin_w     + (size_t)(mtile*16 + n16)*4096;
        const float* B0 = lin_enc_w + (size_t)n16*16384;
        const float* B1 = lin_enc_w + (size_t)(16+n16)*16384;
        enc_tile<4,64>(Ar, B0, B1, ks*1024 + w*128, kg, acc0, acc1);
    } else {                  // bias encoder: M=256, K=64 (waves 2..7 idle)
        mtile = b - 576; slot = 0; nodebase = 768;
        if (w < 2) {
            const float* Ar = bias_w     + (size_t)(mtile*16 + n16)*64;
            const float* B0 = bias_enc_w + (size_t)n16*128;
            const float* B1 = bias_enc_w + (size_t)(16+n16)*128;
            enc_tile<1,0>(Ar, B0, B1, w*32, kg, acc0, acc1);
        }
    }

    // in-block reduction of the 8 waves' 16x32 tiles
    __shared__ float R[8*16*32];
#pragma unroll
    for (int r = 0; r < 4; ++r) {
        R[(w*16 + kg*4 + r)*32 + n16]      = acc0[r];
        R[(w*16 + kg*4 + r)*32 + 16 + n16] = acc1[r];
    }
    __syncthreads();
    {
        float s = 0.f;
#pragma unroll
        for (int p = 0; p < 8; ++p) s += R[p*512 + tid];
        int nl = tid >> 5, h = tid & 31;
        int node = nodebase + mtile*16 + nl;
        P[((size_t)slot*1024 + node)*32 + h] = s;
    }
}

// ---------------------------------------------------------------------------
// k_z1: 257 blocks x 4 rows (was 129 x 8 -> half the CUs idle).
// ---------------------------------------------------------------------------
__global__ __launch_bounds__(256) void k_z1(
    const float* __restrict__ P,
    const float* __restrict__ conv_enc_b,
    const float* __restrict__ lin_enc_b,
    const float* __restrict__ bias_enc_b,
    const float* __restrict__ embed_tab,
    const int* __restrict__ prims,
    const float* __restrict__ gcn_w1,
    const float* __restrict__ dinv,
    float* __restrict__ Z1s)
{
    __shared__ float El[4*32], Ml[4*32];
    int tid = threadIdx.x;
    int i0 = blockIdx.x * 4;
    if (tid < 128) {
        int rl = tid >> 5, h = tid & 31;
        int i = i0 + rl;
        if (i < 1025) {
            float e, m;
            if (i == 0) { e = 1.0f; m = 1.0f; }
            else {
                int node = i - 1;
                int ns; float bias;
                if (node < 512)      { ns = 16; bias = conv_enc_b[h]; }
                else if (node < 768) { ns = 4;  bias = lin_enc_b[h];  }
                else                 { ns = 1;  bias = bias_enc_b[h]; }
                float s = bias;
                for (int sl = 0; sl < ns; ++sl)
                    s += P[((size_t)sl*1024 + node)*32 + h];
                e = s;
                m = embed_tab[prims[node]*32 + h];
            }
            El[rl*32+h] = e; Ml[rl*32+h] = m;
        }
    }
    __syncthreads();
    if (tid < 96) {
        int rl = tid / 24, c4 = tid % 24;
        int i = i0 + rl;
        if (i < 1025) {
            float a0=0,a1=0,a2=0,a3=0;
            for (int h = 0; h < 32; ++h) {
                float e = El[rl*32+h], m = Ml[rl*32+h];
                float4 wa = *(const float4*)(gcn_w1 + h*96 + c4*4);
                float4 wb = *(const float4*)(gcn_w1 + (h+32)*96 + c4*4);
                float4 wc = *(const float4*)(gcn_w1 + (h+64)*96 + c4*4);
                a0 += e*(wa.x+wb.x) + m*wc.x;
                a1 += e*(wa.y+wb.y) + m*wc.y;
                a2 += e*(wa.z+wb.z) + m*wc.z;
                a3 += e*(wa.w+wb.w) + m*wc.w;
            }
            float di = dinv[i];
            float* o = Z1s + (size_t)i*96 + c4*4;
            o[0] = di*a0; o[1] = di*a1; o[2] = di*a2; o[3] = di*a3;
        }
    }
}

// ---------------------------------------------------------------------------
// k_prop: 512 threads (8 waves/CU, was 4); j-loop stride 10 -> 20.
// ---------------------------------------------------------------------------
__global__ __launch_bounds__(512) void k_prop(
    const float* __restrict__ Zs, const int* __restrict__ adj,
    const float* __restrict__ dinv, const float* __restrict__ gcn_w2,
    float* __restrict__ Zout, unsigned short* __restrict__ Xb, int mode)
{
    __shared__ float adjf[4*1025];
    __shared__ float red[4*96];
    int tid = threadIdx.x;
    int i0 = blockIdx.x * 4;
    int nr = (1025 - i0 < 4) ? (1025 - i0) : 4;
    for (int idx = tid; idx < nr*1025; idx += 512)
        adjf[idx] = (float)adj[(size_t)i0*1025 + idx];
    for (int idx = nr*1025 + tid; idx < 4*1025; idx += 512)
        adjf[idx] = 0.f;                                 // last-block tail
    if (tid < 384) red[tid] = 0.f;
    __syncthreads();
    if (tid < nr) adjf[tid*1025 + i0 + tid] += 1.0f;     // + identity
    __syncthreads();

    if (tid < 480) {
        int c4 = tid % 24, jg = tid / 24;                // 20 j-groups
        float acc[4][4] = {};
        for (int j = jg; j < 1025; j += 20) {
            const float4 z = *(const float4*)(Zs + (size_t)j*96 + c4*4);
#pragma unroll
            for (int r = 0; r < 4; ++r) {
                float av = adjf[r*1025 + j];
                acc[r][0] += av*z.x; acc[r][1] += av*z.y;
                acc[r][2] += av*z.z; acc[r][3] += av*z.w;
            }
        }
#pragma unroll
        for (int r = 0; r < 4; ++r) {
            atomicAdd(&red[r*96 + c4*4 + 0], acc[r][0]);
            atomicAdd(&red[r*96 + c4*4 + 1], acc[r][1]);
            atomicAdd(&red[r*96 + c4*4 + 2], acc[r][2]);
            atomicAdd(&red[r*96 + c4*4 + 3], acc[r][3]);
        }
    }
    __syncthreads();

    if (mode == 0) {
        if (tid < 96) {
            int rl = tid / 24, c4 = tid % 24;
            int i = i0 + rl;
            if (rl < nr) {
                float di = dinv[i];
                float o0=0,o1=0,o2=0,o3=0;
                for (int c = 0; c < 96; ++c) {
                    float hv = red[rl*96+c]*di; hv = hv > 0.f ? hv : 0.f;
                    float4 w2 = *(const float4*)(gcn_w2 + c*96 + c4*4);
                    o0 += hv*w2.x; o1 += hv*w2.y; o2 += hv*w2.z; o3 += hv*w2.w;
                }
                float* o = Zout + (size_t)i*96 + c4*4;
                o[0] = di*o0; o[1] = di*o1; o[2] = di*o2; o[3] = di*o3;
            }
        }
    } else {
        for (int idx = tid; idx < nr*96; idx += 512) {
            int rl = idx / 96, c = idx % 96;
            int i = i0 + rl;
            __hip_bfloat16 hb = __float2bfloat16(dinv[i]*red[rl*96+c]);
            Xb[(size_t)i*96 + c] = *(unsigned short*)&hb;
        }
    }
}

// ---------------------------------------------------------------------------
// k_dec: node-split x2 vs previous (conv 4 quarters, lin 2 halves, bias 2)
// -> 1218 blocks (~4.8/CU) of store concurrency; mt loop 16 -> 8.
// ---------------------------------------------------------------------------
__global__ __launch_bounds__(256) void k_dec(
    const unsigned short* __restrict__ Xb,
    const float* __restrict__ cW, const float* __restrict__ cB,
    const float* __restrict__ lW, const float* __restrict__ lB,
    const float* __restrict__ bW, const float* __restrict__ bB,
    float* __restrict__ out)
{
    int b = blockIdx.x, tid = threadIdx.x;
    int w = tid >> 6, lane = tid & 63;
    int n16 = lane & 15, kg = lane >> 4;

    const float *W, *Bv;
    int g0, kcw, ncols, div, ostride;
    size_t obase;
    if (b < 1152) {                      // conv decoder: 288 kb x 4 node-qtrs
        int kb = b >> 2, mb = b & 3;
        W = cW; Bv = cB; g0 = 1 + mb*128; kcw = kb*128 + w*32; ncols = 36864;
        div = 576; obase = (size_t)mb*128*36864; ostride = 36864;
    } else if (b < 1216) {               // lin decoder: 32 kb x 2 node-halves
        int bb = b - 1152; int kb = bb >> 1, mq = bb & 1;
        W = lW; Bv = lB; g0 = 513 + mq*128; kcw = kb*128 + w*32; ncols = 4096;
        div = 64; obase = (size_t)18874368 + (size_t)mq*128*4096; ostride = 4096;
    } else {                             // bias decoder: 2 node-halves
        int mq = b - 1216;
        W = bW; Bv = bB; g0 = 769 + mq*128; kcw = w*32; ncols = 64;
        div = 0; obase = (size_t)19922944 + (size_t)mq*128*64; ostride = 64;
    }
    if (kcw >= ncols) return;

    int kc_a = kcw + n16, kc_b = kcw + 16 + n16;
    int row_a = div ? kc_a + (kc_a/div)*div : kc_a;   // padded row index
    int row_b = div ? kc_b + (kc_b/div)*div : kc_b;
    const float* Wa = W + (size_t)row_a*96 + kg*8;
    const float* Wb = W + (size_t)row_b*96 + kg*8;
    bf16x8 ba0 = cvt8(Wa);
    bf16x8 ba1 = cvt8(Wa + 32);
    bf16x8 ba2 = cvt8(Wa + 64);
    bf16x8 bb0 = cvt8(Wb);
    bf16x8 bb1 = cvt8(Wb + 32);
    bf16x8 bb2 = cvt8(Wb + 64);
    float bva = Bv[row_a], bvb = Bv[row_b];

#pragma unroll 2
    for (int mt = 0; mt < 8; ++mt) {
        const unsigned short* Ar = Xb + (size_t)(g0 + mt*16 + n16)*96 + kg*8;
        bf16x8 a0 = *(const bf16x8*)(Ar);
        bf16x8 a1 = *(const bf16x8*)(Ar + 32);
        bf16x8 a2 = *(const bf16x8*)(Ar + 64);
        f32x4 acc0 = {0.f,0.f,0.f,0.f}, acc1 = {0.f,0.f,0.f,0.f};
        acc0 = MFMA16(a0, ba0, acc0);
        acc0 = MFMA16(a1, ba1, acc0);
        acc0 = MFMA16(a2, ba2, acc0);
        acc1 = MFMA16(a0, bb0, acc1);
        acc1 = MFMA16(a1, bb1, acc1);
        acc1 = MFMA16(a2, bb2, acc1);
#pragma unroll
        for (int r = 0; r < 4; ++r) {
            int node = mt*16 + kg*4 + r;
            out[obase + (size_t)node*ostride + kc_a] = acc0[r] + bva;
            out[obase + (size_t)node*ostride + kc_b] = acc1[r] + bvb;
        }
    }
}

// ---------------------------------------------------------------------------
extern "C" void kernel_launch(void* const* d_in, const int* in_sizes, int n_in,
                              void* d_out, int out_size, void* d_ws, size_t ws_size,
                              hipStream_t stream)
{
    const float* conv_w     = (const float*)d_in[0];
    const float* lin_w      = (const float*)d_in[1];
    const float* bias_w     = (const float*)d_in[2];
    const float* conv_enc_w = (const float*)d_in[3];
    const float* conv_enc_b = (const float*)d_in[4];
    const float* lin_enc_w  = (const float*)d_in[5];
    const float* lin_enc_b  = (const float*)d_in[6];
    const float* bias_enc_w = (const float*)d_in[7];
    const float* bias_enc_b = (const float*)d_in[8];
    const float* gcn_w1     = (const float*)d_in[9];
    const float* gcn_w2     = (const float*)d_in[10];
    const float* conv_dec_w = (const float*)d_in[11];
    const float* conv_dec_b = (const float*)d_in[12];
    const float* lin_dec_w  = (const float*)d_in[13];
    const float* lin_dec_b  = (const float*)d_in[14];
    const float* bias_dec_w = (const float*)d_in[15];
    const float* bias_dec_b = (const float*)d_in[16];
    const float* embed_tab  = (const float*)d_in[17];
    const int*   adj        = (const int*)d_in[18];
    const int*   prims      = (const int*)d_in[19];

    // workspace layout (floats): P 16*1024*32 | Z1s | Z2s | dinv | Xb(bf16)
    float* P    = (float*)d_ws;             // 524288 f = 2 MB
    float* Z1s  = P + (size_t)16*1024*32;   // 98400 f
    float* Z2s  = Z1s + 1025*96;            // 98400 f
    float* dinv = Z2s + 1025*96;            // 1056 f
    unsigned short* Xb = (unsigned short*)(dinv + 1056);  // 1025*96 bf16

    k_enc<<<608, 512, 0, stream>>>(conv_w, lin_w, bias_w,
                                   conv_enc_w, lin_enc_w, bias_enc_w,
                                   adj, P, dinv);
    k_z1<<<257, 256, 0, stream>>>(P, conv_enc_b, lin_enc_b, bias_enc_b,
                                  embed_tab, prims, gcn_w1, dinv, Z1s);
    k_prop<<<257, 512, 0, stream>>>(Z1s, adj, dinv, gcn_w2, Z2s, Xb, 0);
    k_prop<<<257, 512, 0, stream>>>(Z2s, adj, dinv, gcn_w2, Z2s, Xb, 1);
    k_dec<<<1218, 256, 0, stream>>>(Xb, conv_dec_w, conv_dec_b,
                                    lin_dec_w, lin_dec_b,
                                    bias_dec_w, bias_dec_b,
                                    (float*)d_out);
}

// Round 4
// 334.314 us; speedup vs baseline: 1.5442x; 1.0013x over previous
//
#include <hip/hip_runtime.h>
#include <hip/hip_bf16.h>

// ---------------------------------------------------------------------------
// GHN (float32 I/O): encode (3 gathered GEMMs, bf16 MFMA, f32 acc)
//   -> 2-layer GCN (pure f32 vector) -> decode (gathered GEMMs, MFMA) -> f32
// R4: k_enc rewritten with LDS-staged COALESCED loads (the 16-row strided
// direct loads fragmented every VMEM instr into 16 segments; wave-count
// insensitivity across R1->R3 showed latency-hiding wasn't the fix).
// k_z1 / k_prop / k_dec unchanged from R3 (passed).
// ---------------------------------------------------------------------------

typedef __attribute__((ext_vector_type(8))) __bf16 bf16x8;
typedef __attribute__((ext_vector_type(4))) __bf16 bf16x4;
typedef __attribute__((ext_vector_type(4))) float f32x4;

#define MFMA16(a,b,c) __builtin_amdgcn_mfma_f32_16x16x32_bf16((a),(b),(c),0,0,0)

__device__ __forceinline__ bf16x8 cvt8(const float* p) {
    float4 a = *(const float4*)p;
    float4 b = *(const float4*)(p + 4);
    bf16x8 r;
    r[0]=(__bf16)a.x; r[1]=(__bf16)a.y; r[2]=(__bf16)a.z; r[3]=(__bf16)a.w;
    r[4]=(__bf16)b.x; r[5]=(__bf16)b.y; r[6]=(__bf16)b.z; r[7]=(__bf16)b.w;
    return r;
}

// legacy direct-load tile (kept for bias encoder, K=64)
template<int KSTEPS, int DIV>
__device__ __forceinline__ void enc_tile(const float* Ar,
                                         const float* B0,
                                         const float* B1,
                                         int kw, int kg, f32x4& acc0, f32x4& acc1)
{
#pragma unroll
    for (int s = 0; s < KSTEPS; ++s) {
        int k = kw + s*32 + kg*8;
        int col = DIV ? (k + (k/DIV)*DIV) : k;
        bf16x8 a  = cvt8(Ar + k);
        bf16x8 b0 = cvt8(B0 + col);
        bf16x8 b1 = cvt8(B1 + col);
        acc0 = MFMA16(a, b0, acc0);
        acc1 = MFMA16(a, b1, acc1);
    }
}

// ---------------------------------------------------------------------------
// Staged encoder tile: per 256-col window, coalesced f32->bf16 staging of
// A (16 rows) and B (32 enc rows) into LDS, then ds_read_b128 fragments.
// Row stride 264 bf16 (=132 words, ==4 mod 32 -> <=2-way bank aliasing).
// 4 waves split the 8 K-steps of each window; partials reduced by caller.
// ---------------------------------------------------------------------------
template<int NSUB, int DIV>
__device__ __forceinline__ void enc_staged(
    const float* __restrict__ Arow0, size_t AST,
    const float* __restrict__ Wenc,  size_t WST,
    int kslotbase, int tid, int w, int lane,
    __bf16* As, __bf16* Bs, f32x4& acc0, f32x4& acc1)
{
    const int n16 = lane & 15, kg = lane >> 4;
    for (int sub = 0; sub < NSUB; ++sub) {
        const int kbase = kslotbase + sub*256;
        // ---- stage A: 16 rows x 256 f32 = 1024 float4, coalesced
#pragma unroll
        for (int i = 0; i < 4; ++i) {
            int idx = tid + i*256;
            int row = idx >> 6, c4 = idx & 63;
            float4 v = *(const float4*)(Arow0 + (size_t)row*AST + kbase + c4*4);
            bf16x4 o;
            o[0]=(__bf16)v.x; o[1]=(__bf16)v.y; o[2]=(__bf16)v.z; o[3]=(__bf16)v.w;
            *(bf16x4*)(As + row*264 + c4*4) = o;
        }
        // ---- stage B: 32 enc rows x 256 cols (gathered), coalesced
#pragma unroll
        for (int i = 0; i < 8; ++i) {
            int idx = tid + i*256;
            int row = idx >> 6, c4 = idx & 63;
            int k = kbase + c4*4;
            int gcol = DIV ? (k + (k/DIV)*DIV) : k;   // 4 | DIV -> granule-safe
            float4 v = *(const float4*)(Wenc + (size_t)row*WST + gcol);
            bf16x4 o;
            o[0]=(__bf16)v.x; o[1]=(__bf16)v.y; o[2]=(__bf16)v.z; o[3]=(__bf16)v.w;
            *(bf16x4*)(Bs + row*264 + c4*4) = o;
        }
        __syncthreads();
        // ---- compute: wave w takes K-steps {2w, 2w+1} of this window
#pragma unroll
        for (int s2 = 0; s2 < 2; ++s2) {
            int kl = (w*2 + s2)*32 + kg*8;
            bf16x8 a  = *(const bf16x8*)(As + n16*264 + kl);
            bf16x8 b0 = *(const bf16x8*)(Bs + n16*264 + kl);
            bf16x8 b1 = *(const bf16x8*)(Bs + (16+n16)*264 + kl);
            acc0 = MFMA16(a, b0, acc0);
            acc1 = MFMA16(a, b1, acc1);
        }
        __syncthreads();   // WAR: next window rewrites As/Bs
    }
}

// ---------------------------------------------------------------------------
// k_enc: 256 thr (4 waves). conv: 32 mtiles x 16 kslots (2304 cols = 9 subs);
// lin: 16 mtiles x 4 kslots (1024 cols = 4 subs); bias: direct; dinv: 16 blks.
// ---------------------------------------------------------------------------
__global__ __launch_bounds__(256) void k_enc(
    const float* __restrict__ conv_w,
    const float* __restrict__ lin_w,
    const float* __restrict__ bias_w,
    const float* __restrict__ conv_enc_w,
    const float* __restrict__ lin_enc_w,
    const float* __restrict__ bias_enc_w,
    const int* __restrict__ adj,
    float* __restrict__ P, float* __restrict__ dinv)
{
    __shared__ char smem_raw[(16+32)*264*2];   // As+Bs (25.3 KB); aliased by R
    __bf16* As = (__bf16*)smem_raw;
    __bf16* Bs = As + 16*264;
    float*  R  = (float*)smem_raw;             // 4*16*32 f32 = 8 KB (post-sync)

    int b = blockIdx.x, tid = threadIdx.x;
    int w = tid >> 6, lane = tid & 63;
    int n16 = lane & 15, kg = lane >> 4;

    if (b >= 592) {  // ---- dinv: 16 blocks x 4 waves = 64 waves
        int wid = (b - 592)*4 + w;
        for (int r = wid; r < 1025; r += 64) {
            const int* row = adj + (size_t)r*1025;
            int s = 0;
#pragma unroll
            for (int i = 0; i <= 16; ++i) {
                int j = lane + i*64;
                if (j < 1025) s += row[j];
            }
#pragma unroll
            for (int off = 32; off; off >>= 1) s += __shfl_xor(s, off, 64);
            if (lane == 0) dinv[r] = 1.0f / sqrtf((float)s + 1.0f);
        }
        return;
    }

    f32x4 acc0 = {0.f,0.f,0.f,0.f}, acc1 = {0.f,0.f,0.f,0.f};
    int slot, nodebase, mtile;
    if (b < 512) {            // conv encoder: M=512, K=36864
        mtile = b >> 4; int ks = b & 15;
        slot = ks; nodebase = 0;
        enc_staged<9,576>(conv_w + (size_t)mtile*16*36864, 36864,
                          conv_enc_w, 147456,
                          ks*2304, tid, w, lane, As, Bs, acc0, acc1);
    } else if (b < 576) {     // lin encoder: M=256, K=4096
        int bb = b - 512; mtile = bb >> 2; int ks = bb & 3;
        slot = ks; nodebase = 512;
        enc_staged<4,64>(lin_w + (size_t)mtile*16*4096, 4096,
                         lin_enc_w, 16384,
                         ks*1024, tid, w, lane, As, Bs, acc0, acc1);
    } else {                  // bias encoder: M=256, K=64 (waves 2,3 idle)
        mtile = b - 576; slot = 0; nodebase = 768;
        if (w < 2) {
            const float* Ar = bias_w     + (size_t)(mtile*16 + n16)*64;
            const float* B0 = bias_enc_w + (size_t)n16*128;
            const float* B1 = bias_enc_w + (size_t)(16+n16)*128;
            enc_tile<1,0>(Ar, B0, B1, w*32, kg, acc0, acc1);
        }
        __syncthreads();      // align with staged path's final sync state
    }

    // in-block reduction of the 4 waves' 16x32 tiles (R aliases As/Bs)
#pragma unroll
    for (int r = 0; r < 4; ++r) {
        R[(w*16 + kg*4 + r)*32 + n16]      = acc0[r];
        R[(w*16 + kg*4 + r)*32 + 16 + n16] = acc1[r];
    }
    __syncthreads();
    for (int e = tid; e < 512; e += 256) {
        float s = R[e] + R[512+e] + R[1024+e] + R[1536+e];
        int nl = e >> 5, h = e & 31;
        int node = nodebase + mtile*16 + nl;
        P[((size_t)slot*1024 + node)*32 + h] = s;
    }
}

// ---------------------------------------------------------------------------
// k_z1: 257 blocks x 4 rows (unchanged from R3)
// ---------------------------------------------------------------------------
__global__ __launch_bounds__(256) void k_z1(
    const float* __restrict__ P,
    const float* __restrict__ conv_enc_b,
    const float* __restrict__ lin_enc_b,
    const float* __restrict__ bias_enc_b,
    const float* __restrict__ embed_tab,
    const int* __restrict__ prims,
    const float* __restrict__ gcn_w1,
    const float* __restrict__ dinv,
    float* __restrict__ Z1s)
{
    __shared__ float El[4*32], Ml[4*32];
    int tid = threadIdx.x;
    int i0 = blockIdx.x * 4;
    if (tid < 128) {
        int rl = tid >> 5, h = tid & 31;
        int i = i0 + rl;
        if (i < 1025) {
            float e, m;
            if (i == 0) { e = 1.0f; m = 1.0f; }
            else {
                int node = i - 1;
                int ns; float bias;
                if (node < 512)      { ns = 16; bias = conv_enc_b[h]; }
                else if (node < 768) { ns = 4;  bias = lin_enc_b[h];  }
                else                 { ns = 1;  bias = bias_enc_b[h]; }
                float s = bias;
                for (int sl = 0; sl < ns; ++sl)
                    s += P[((size_t)sl*1024 + node)*32 + h];
                e = s;
                m = embed_tab[prims[node]*32 + h];
            }
            El[rl*32+h] = e; Ml[rl*32+h] = m;
        }
    }
    __syncthreads();
    if (tid < 96) {
        int rl = tid / 24, c4 = tid % 24;
        int i = i0 + rl;
        if (i < 1025) {
            float a0=0,a1=0,a2=0,a3=0;
            for (int h = 0; h < 32; ++h) {
                float e = El[rl*32+h], m = Ml[rl*32+h];
                float4 wa = *(const float4*)(gcn_w1 + h*96 + c4*4);
                float4 wb = *(const float4*)(gcn_w1 + (h+32)*96 + c4*4);
                float4 wc = *(const float4*)(gcn_w1 + (h+64)*96 + c4*4);
                a0 += e*(wa.x+wb.x) + m*wc.x;
                a1 += e*(wa.y+wb.y) + m*wc.y;
                a2 += e*(wa.z+wb.z) + m*wc.z;
                a3 += e*(wa.w+wb.w) + m*wc.w;
            }
            float di = dinv[i];
            float* o = Z1s + (size_t)i*96 + c4*4;
            o[0] = di*a0; o[1] = di*a1; o[2] = di*a2; o[3] = di*a3;
        }
    }
}

// ---------------------------------------------------------------------------
// k_prop: unchanged from R3 (512 thr, 8 waves)
// ---------------------------------------------------------------------------
__global__ __launch_bounds__(512) void k_prop(
    const float* __restrict__ Zs, const int* __restrict__ adj,
    const float* __restrict__ dinv, const float* __restrict__ gcn_w2,
    float* __restrict__ Zout, unsigned short* __restrict__ Xb, int mode)
{
    __shared__ float adjf[4*1025];
    __shared__ float red[4*96];
    int tid = threadIdx.x;
    int i0 = blockIdx.x * 4;
    int nr = (1025 - i0 < 4) ? (1025 - i0) : 4;
    for (int idx = tid; idx < nr*1025; idx += 512)
        adjf[idx] = (float)adj[(size_t)i0*1025 + idx];
    for (int idx = nr*1025 + tid; idx < 4*1025; idx += 512)
        adjf[idx] = 0.f;
    if (tid < 384) red[tid] = 0.f;
    __syncthreads();
    if (tid < nr) adjf[tid*1025 + i0 + tid] += 1.0f;
    __syncthreads();

    if (tid < 480) {
        int c4 = tid % 24, jg = tid / 24;
        float acc[4][4] = {};
        for (int j = jg; j < 1025; j += 20) {
            const float4 z = *(const float4*)(Zs + (size_t)j*96 + c4*4);
#pragma unroll
            for (int r = 0; r < 4; ++r) {
                float av = adjf[r*1025 + j];
                acc[r][0] += av*z.x; acc[r][1] += av*z.y;
                acc[r][2] += av*z.z; acc[r][3] += av*z.w;
            }
        }
#pragma unroll
        for (int r = 0; r < 4; ++r) {
            atomicAdd(&red[r*96 + c4*4 + 0], acc[r][0]);
            atomicAdd(&red[r*96 + c4*4 + 1], acc[r][1]);
            atomicAdd(&red[r*96 + c4*4 + 2], acc[r][2]);
            atomicAdd(&red[r*96 + c4*4 + 3], acc[r][3]);
        }
    }
    __syncthreads();

    if (mode == 0) {
        if (tid < 96) {
            int rl = tid / 24, c4 = tid % 24;
            int i = i0 + rl;
            if (rl < nr) {
                float di = dinv[i];
                float o0=0,o1=0,o2=0,o3=0;
                for (int c = 0; c < 96; ++c) {
                    float hv = red[rl*96+c]*di; hv = hv > 0.f ? hv : 0.f;
                    float4 w2 = *(const float4*)(gcn_w2 + c*96 + c4*4);
                    o0 += hv*w2.x; o1 += hv*w2.y; o2 += hv*w2.z; o3 += hv*w2.w;
                }
                float* o = Zout + (size_t)i*96 + c4*4;
                o[0] = di*o0; o[1] = di*o1; o[2] = di*o2; o[3] = di*o3;
            }
        }
    } else {
        for (int idx = tid; idx < nr*96; idx += 512) {
            int rl = idx / 96, c = idx % 96;
            int i = i0 + rl;
            __hip_bfloat16 hb = __float2bfloat16(dinv[i]*red[rl*96+c]);
            Xb[(size_t)i*96 + c] = *(unsigned short*)&hb;
        }
    }
}

// ---------------------------------------------------------------------------
// k_dec: unchanged from R3 (node-split x2, 1218 blocks)
// ---------------------------------------------------------------------------
__global__ __launch_bounds__(256) void k_dec(
    const unsigned short* __restrict__ Xb,
    const float* __restrict__ cW, const float* __restrict__ cB,
    const float* __restrict__ lW, const float* __restrict__ lB,
    const float* __restrict__ bW, const float* __restrict__ bB,
    float* __restrict__ out)
{
    int b = blockIdx.x, tid = threadIdx.x;
    int w = tid >> 6, lane = tid & 63;
    int n16 = lane & 15, kg = lane >> 4;

    const float *W, *Bv;
    int g0, kcw, ncols, div, ostride;
    size_t obase;
    if (b < 1152) {                      // conv decoder: 288 kb x 4 node-qtrs
        int kb = b >> 2, mb = b & 3;
        W = cW; Bv = cB; g0 = 1 + mb*128; kcw = kb*128 + w*32; ncols = 36864;
        div = 576; obase = (size_t)mb*128*36864; ostride = 36864;
    } else if (b < 1216) {               // lin decoder: 32 kb x 2 node-halves
        int bb = b - 1152; int kb = bb >> 1, mq = bb & 1;
        W = lW; Bv = lB; g0 = 513 + mq*128; kcw = kb*128 + w*32; ncols = 4096;
        div = 64; obase = (size_t)18874368 + (size_t)mq*128*4096; ostride = 4096;
    } else {                             // bias decoder: 2 node-halves
        int mq = b - 1216;
        W = bW; Bv = bB; g0 = 769 + mq*128; kcw = w*32; ncols = 64;
        div = 0; obase = (size_t)19922944 + (size_t)mq*128*64; ostride = 64;
    }
    if (kcw >= ncols) return;

    int kc_a = kcw + n16, kc_b = kcw + 16 + n16;
    int row_a = div ? kc_a + (kc_a/div)*div : kc_a;
    int row_b = div ? kc_b + (kc_b/div)*div : kc_b;
    const float* Wa = W + (size_t)row_a*96 + kg*8;
    const float* Wb = W + (size_t)row_b*96 + kg*8;
    bf16x8 ba0 = cvt8(Wa);
    bf16x8 ba1 = cvt8(Wa + 32);
    bf16x8 ba2 = cvt8(Wa + 64);
    bf16x8 bb0 = cvt8(Wb);
    bf16x8 bb1 = cvt8(Wb + 32);
    bf16x8 bb2 = cvt8(Wb + 64);
    float bva = Bv[row_a], bvb = Bv[row_b];

#pragma unroll 2
    for (int mt = 0; mt < 8; ++mt) {
        const unsigned short* Ar = Xb + (size_t)(g0 + mt*16 + n16)*96 + kg*8;
        bf16x8 a0 = *(const bf16x8*)(Ar);
        bf16x8 a1 = *(const bf16x8*)(Ar + 32);
        bf16x8 a2 = *(const bf16x8*)(Ar + 64);
        f32x4 acc0 = {0.f,0.f,0.f,0.f}, acc1 = {0.f,0.f,0.f,0.f};
        acc0 = MFMA16(a0, ba0, acc0);
        acc0 = MFMA16(a1, ba1, acc0);
        acc0 = MFMA16(a2, ba2, acc0);
        acc1 = MFMA16(a0, bb0, acc1);
        acc1 = MFMA16(a1, bb1, acc1);
        acc1 = MFMA16(a2, bb2, acc1);
#pragma unroll
        for (int r = 0; r < 4; ++r) {
            int node = mt*16 + kg*4 + r;
            out[obase + (size_t)node*ostride + kc_a] = acc0[r] + bva;
            out[obase + (size_t)node*ostride + kc_b] = acc1[r] + bvb;
        }
    }
}

// ---------------------------------------------------------------------------
extern "C" void kernel_launch(void* const* d_in, const int* in_sizes, int n_in,
                              void* d_out, int out_size, void* d_ws, size_t ws_size,
                              hipStream_t stream)
{
    const float* conv_w     = (const float*)d_in[0];
    const float* lin_w      = (const float*)d_in[1];
    const float* bias_w     = (const float*)d_in[2];
    const float* conv_enc_w = (const float*)d_in[3];
    const float* conv_enc_b = (const float*)d_in[4];
    const float* lin_enc_w  = (const float*)d_in[5];
    const float* lin_enc_b  = (const float*)d_in[6];
    const float* bias_enc_w = (const float*)d_in[7];
    const float* bias_enc_b = (const float*)d_in[8];
    const float* gcn_w1     = (const float*)d_in[9];
    const float* gcn_w2     = (const float*)d_in[10];
    const float* conv_dec_w = (const float*)d_in[11];
    const float* conv_dec_b = (const float*)d_in[12];
    const float* lin_dec_w  = (const float*)d_in[13];
    const float* lin_dec_b  = (const float*)d_in[14];
    const float* bias_dec_w = (const float*)d_in[15];
    const float* bias_dec_b = (const float*)d_in[16];
    const float* embed_tab  = (const float*)d_in[17];
    const int*   adj        = (const int*)d_in[18];
    const int*   prims      = (const int*)d_in[19];

    // workspace layout (floats): P 16*1024*32 | Z1s | Z2s | dinv | Xb(bf16)
    float* P    = (float*)d_ws;             // 524288 f = 2 MB
    float* Z1s  = P + (size_t)16*1024*32;   // 98400 f
    float* Z2s  = Z1s + 1025*96;            // 98400 f
    float* dinv = Z2s + 1025*96;            // 1056 f
    unsigned short* Xb = (unsigned short*)(dinv + 1056);  // 1025*96 bf16

    k_enc<<<608, 256, 0, stream>>>(conv_w, lin_w, bias_w,
                                   conv_enc_w, lin_enc_w, bias_enc_w,
                                   adj, P, dinv);
    k_z1<<<257, 256, 0, stream>>>(P, conv_enc_b, lin_enc_b, bias_enc_b,
                                  embed_tab, prims, gcn_w1, dinv, Z1s);
    k_prop<<<257, 512, 0, stream>>>(Z1s, adj, dinv, gcn_w2, Z2s, Xb, 0);
    k_prop<<<257, 512, 0, stream>>>(Z2s, adj, dinv, gcn_w2, Z2s, Xb, 1);
    k_dec<<<1218, 256, 0, stream>>>(Xb, conv_dec_w, conv_dec_b,
                                    lin_dec_w, lin_dec_b,
                                    bias_dec_w, bias_dec_b,
                                    (float*)d_out);
}

// Round 5
// 303.756 us; speedup vs baseline: 1.6995x; 1.1006x over previous
//
#include <hip/hip_runtime.h>
#include <hip/hip_bf16.h>

// ---------------------------------------------------------------------------
// GHN (float32 I/O): encode (3 gathered GEMMs, bf16 MFMA, f32 acc)
//   -> 2-layer GCN -> decode (gathered GEMMs, MFMA) -> f32
// R5: k_enc/k_z1/k_dec reverted to R1 (fastest measured). Propagation
// restructured: old k_prop (257 blocks, full-Zs re-read per block, 101 MB
// L2 traffic, 1 block/CU) replaced by 2-D-split partial kernels with global
// f32 atomicAdd into `red`, plus tiny finish kernels.
// ---------------------------------------------------------------------------

typedef __attribute__((ext_vector_type(8))) __bf16 bf16x8;
typedef __attribute__((ext_vector_type(4))) float f32x4;

#define MFMA16(a,b,c) __builtin_amdgcn_mfma_f32_16x16x32_bf16((a),(b),(c),0,0,0)

__device__ __forceinline__ bf16x8 cvt8(const float* p) {
    float4 a = *(const float4*)p;
    float4 b = *(const float4*)(p + 4);
    bf16x8 r;
    r[0]=(__bf16)a.x; r[1]=(__bf16)a.y; r[2]=(__bf16)a.z; r[3]=(__bf16)a.w;
    r[4]=(__bf16)b.x; r[5]=(__bf16)b.y; r[6]=(__bf16)b.z; r[7]=(__bf16)b.w;
    return r;
}

template<int KSTEPS, int DIV>
__device__ __forceinline__ void enc_tile(const float* Ar,
                                         const float* B0,
                                         const float* B1,
                                         int kw, int kg, f32x4& acc0, f32x4& acc1)
{
#pragma unroll
    for (int s = 0; s < KSTEPS; ++s) {
        int k = kw + s*32 + kg*8;
        int col = DIV ? (k + (k/DIV)*DIV) : k;   // gathered (padded) column
        bf16x8 a  = cvt8(Ar + k);
        bf16x8 b0 = cvt8(B0 + col);
        bf16x8 b1 = cvt8(B1 + col);
        acc0 = MFMA16(a, b0, acc0);
        acc1 = MFMA16(a, b1, acc1);
    }
}

// ---------------------------------------------------------------------------
// k_enc: R1-exact (fastest measured variant; insensitive to staging/waves).
// ---------------------------------------------------------------------------
__global__ __launch_bounds__(256) void k_enc(
    const float* __restrict__ conv_w,
    const float* __restrict__ lin_w,
    const float* __restrict__ bias_w,
    const float* __restrict__ conv_enc_w,
    const float* __restrict__ lin_enc_w,
    const float* __restrict__ bias_enc_w,
    const int* __restrict__ adj,
    float* __restrict__ P, float* __restrict__ dinv)
{
    int b = blockIdx.x, tid = threadIdx.x;
    int w = tid >> 6, lane = tid & 63;
    int n16 = lane & 15, kg = lane >> 4;

    if (b >= 592) {  // ---- dinv rows: dinv[i] = 1/sqrt(1 + sum_j adj[i][j])
        int wid = (b - 592)*4 + w;
        for (int r = wid; r < 1025; r += 256) {
            const int* row = adj + (size_t)r*1025;
            int s = 0;
#pragma unroll
            for (int i = 0; i <= 16; ++i) {
                int j = lane + i*64;
                if (j < 1025) s += row[j];
            }
#pragma unroll
            for (int off = 32; off; off >>= 1) s += __shfl_xor(s, off, 64);
            if (lane == 0) dinv[r] = 1.0f / sqrtf((float)s + 1.0f);
        }
        return;
    }

    f32x4 acc0 = {0.f,0.f,0.f,0.f}, acc1 = {0.f,0.f,0.f,0.f};
    int slot, nodebase, mtile;
    if (b < 512) {            // conv encoder: M=512, K=36864, 16 ks x 4 waves
        mtile = b >> 4; int ks = b & 15;
        slot = ks; nodebase = 0;
        const float* Ar = conv_w     + (size_t)(mtile*16 + n16)*36864;
        const float* B0 = conv_enc_w + (size_t)n16*147456;
        const float* B1 = conv_enc_w + (size_t)(16+n16)*147456;
        enc_tile<18,576>(Ar, B0, B1, ks*2304 + w*576, kg, acc0, acc1);
    } else if (b < 576) {     // lin encoder: M=256, K=4096, 4 ks x 4 waves
        int bb = b - 512; mtile = bb >> 2; int ks = bb & 3;
        slot = ks; nodebase = 512;
        const float* Ar = lin_w     + (size_t)(mtile*16 + n16)*4096;
        const float* B0 = lin_enc_w + (size_t)n16*16384;
        const float* B1 = lin_enc_w + (size_t)(16+n16)*16384;
        enc_tile<8,64>(Ar, B0, B1, ks*1024 + w*256, kg, acc0, acc1);
    } else {                  // bias encoder: M=256, K=64 (waves 2,3 idle)
        mtile = b - 576; slot = 0; nodebase = 768;
        if (w < 2) {
            const float* Ar = bias_w     + (size_t)(mtile*16 + n16)*64;
            const float* B0 = bias_enc_w + (size_t)n16*128;
            const float* B1 = bias_enc_w + (size_t)(16+n16)*128;
            enc_tile<1,0>(Ar, B0, B1, w*32, kg, acc0, acc1);
        }
    }

    // in-block reduction of the 4 waves' 16x32 tiles
    __shared__ float R[4*16*32];
#pragma unroll
    for (int r = 0; r < 4; ++r) {
        R[(w*16 + kg*4 + r)*32 + n16]      = acc0[r];
        R[(w*16 + kg*4 + r)*32 + 16 + n16] = acc1[r];
    }
    __syncthreads();
    for (int e = tid; e < 512; e += 256) {
        float s = R[e] + R[512+e] + R[1024+e] + R[1536+e];
        int nl = e >> 5, h = e & 31;
        int node = nodebase + mtile*16 + nl;
        P[((size_t)slot*1024 + node)*32 + h] = s;
    }
}

// ---------------------------------------------------------------------------
// k_z1: R1-exact + red-zeroing tail (red must be 0 before k_propA phase 1;
// re-zeroed every iteration so workspace poison is harmless).
// ---------------------------------------------------------------------------
__global__ __launch_bounds__(256) void k_z1(
    const float* __restrict__ P,
    const float* __restrict__ conv_enc_b,
    const float* __restrict__ lin_enc_b,
    const float* __restrict__ bias_enc_b,
    const float* __restrict__ embed_tab,
    const int* __restrict__ prims,
    const float* __restrict__ gcn_w1,
    const float* __restrict__ dinv,
    float* __restrict__ Z1s,
    float* __restrict__ red)
{
    __shared__ float El[8*32], Ml[8*32];
    int tid = threadIdx.x;
    int i0 = blockIdx.x * 8;

    // zero red (1025*96 = 98400 floats) across 129 blocks
    for (int idx = blockIdx.x*256 + tid; idx < 98400; idx += 129*256)
        red[idx] = 0.f;

    {
        int rl = tid >> 5, h = tid & 31;
        int i = i0 + rl;
        if (i < 1025) {
            float e, m;
            if (i == 0) { e = 1.0f; m = 1.0f; }
            else {
                int node = i - 1;
                int ns; float bias;
                if (node < 512)      { ns = 16; bias = conv_enc_b[h]; }
                else if (node < 768) { ns = 4;  bias = lin_enc_b[h];  }
                else                 { ns = 1;  bias = bias_enc_b[h]; }
                float s = bias;
                for (int sl = 0; sl < ns; ++sl)
                    s += P[((size_t)sl*1024 + node)*32 + h];
                e = s;
                m = embed_tab[prims[node]*32 + h];
            }
            El[rl*32+h] = e; Ml[rl*32+h] = m;
        }
    }
    __syncthreads();
    if (tid < 192) {
        int rl = tid / 24, c4 = tid % 24;
        int i = i0 + rl;
        if (i < 1025) {
            float a0=0,a1=0,a2=0,a3=0;
            for (int h = 0; h < 32; ++h) {
                float e = El[rl*32+h], m = Ml[rl*32+h];
                float4 wa = *(const float4*)(gcn_w1 + h*96 + c4*4);
                float4 wb = *(const float4*)(gcn_w1 + (h+32)*96 + c4*4);
                float4 wc = *(const float4*)(gcn_w1 + (h+64)*96 + c4*4);
                a0 += e*(wa.x+wb.x) + m*wc.x;
                a1 += e*(wa.y+wb.y) + m*wc.y;
                a2 += e*(wa.z+wb.z) + m*wc.z;
                a3 += e*(wa.w+wb.w) + m*wc.w;
            }
            float di = dinv[i];
            float* o = Z1s + (size_t)i*96 + c4*4;
            o[0] = di*a0; o[1] = di*a1; o[2] = di*a2; o[3] = di*a3;
        }
    }
}

// ---------------------------------------------------------------------------
// k_propA: partial red[i] += sum_{j in chunk} (adj[i][j]+I) * Zs[j].
// Grid 52 i-tiles (20 rows) x 8 j-chunks (128/129 cols) = 416 blocks.
// Zs traffic: 416 x 48KB = 12.5 MB (was 101 MB). Output via global atomicAdd.
// ---------------------------------------------------------------------------
__global__ __launch_bounds__(256) void k_propA(
    const float* __restrict__ Zs, const int* __restrict__ adj,
    float* __restrict__ red)
{
    __shared__ float adjf[20*132];
    int tid = threadIdx.x;
    int jc = blockIdx.x & 7, it = blockIdx.x >> 3;
    int i0 = it * 20;
    int j0 = jc * 128;
    int jlen = (jc == 7) ? 129 : 128;

    // stage 20 x jlen adj slice (+ identity) into LDS, coalesced per row
    for (int idx = tid; idx < 20*132; idx += 256) {
        int row = idx / 132, c = idx % 132;
        int i = i0 + row, j = j0 + c;
        if (c < jlen && i < 1025)
            adjf[row*132 + c] = (float)adj[(size_t)i*1025 + j]
                                + (i == j ? 1.0f : 0.0f);
    }
    __syncthreads();

    if (tid < 240) {
        int c4 = tid % 24, ig = tid / 24;          // ig in [0,10)
        int rA = i0 + ig, rB = i0 + ig + 10;
        float accA[4] = {0,0,0,0}, accB[4] = {0,0,0,0};
        for (int jj = 0; jj < jlen; ++jj) {
            const float4 z = *(const float4*)(Zs + (size_t)(j0+jj)*96 + c4*4);
            float aA = adjf[ig*132 + jj];
            float aB = adjf[(ig+10)*132 + jj];
            accA[0] += aA*z.x; accA[1] += aA*z.y;
            accA[2] += aA*z.z; accA[3] += aA*z.w;
            accB[0] += aB*z.x; accB[1] += aB*z.y;
            accB[2] += aB*z.z; accB[3] += aB*z.w;
        }
        if (rA < 1025) {
            float* o = red + (size_t)rA*96 + c4*4;
            atomicAdd(o+0, accA[0]); atomicAdd(o+1, accA[1]);
            atomicAdd(o+2, accA[2]); atomicAdd(o+3, accA[3]);
        }
        if (rB < 1025) {
            float* o = red + (size_t)rB*96 + c4*4;
            atomicAdd(o+0, accB[0]); atomicAdd(o+1, accB[1]);
            atomicAdd(o+2, accB[2]); atomicAdd(o+3, accB[3]);
        }
    }
}

// ---------------------------------------------------------------------------
// k_propF0: Z2s[i] = dinv[i] * ( relu(dinv[i]*red[i]) @ W2 ); zeroes red
// for phase 2. Grid 205 blocks x 5 rows.
// ---------------------------------------------------------------------------
__global__ __launch_bounds__(256) void k_propF0(
    const float* __restrict__ red, const float* __restrict__ dinv,
    const float* __restrict__ gcn_w2,
    float* __restrict__ Z2s, float* __restrict__ redz)
{
    __shared__ float redl[5*96];
    int tid = threadIdx.x;
    int i0 = blockIdx.x * 5;
    for (int idx = tid; idx < 5*96; idx += 256) {
        int r = idx / 96, c = idx % 96;
        int i = i0 + r;
        if (i < 1025) {
            redl[idx] = red[(size_t)i*96 + c];
            redz[(size_t)i*96 + c] = 0.f;     // ready for phase-2 atomics
        }
    }
    __syncthreads();
    if (tid < 120) {
        int c4 = tid % 24, ig = tid / 24;     // ig in [0,5)
        int i = i0 + ig;
        if (i < 1025) {
            float di = dinv[i];
            float o0=0,o1=0,o2=0,o3=0;
            for (int c = 0; c < 96; ++c) {
                float hv = redl[ig*96 + c] * di; hv = hv > 0.f ? hv : 0.f;
                float4 w2 = *(const float4*)(gcn_w2 + c*96 + c4*4);
                o0 += hv*w2.x; o1 += hv*w2.y; o2 += hv*w2.z; o3 += hv*w2.w;
            }
            float* o = Z2s + (size_t)i*96 + c4*4;
            o[0] = di*o0; o[1] = di*o1; o[2] = di*o2; o[3] = di*o3;
        }
    }
}

// ---------------------------------------------------------------------------
// k_propF1: Xb[i][c] = bf16( dinv[i] * red[i][c] )  (elementwise)
// ---------------------------------------------------------------------------
__global__ __launch_bounds__(256) void k_propF1(
    const float* __restrict__ red, const float* __restrict__ dinv,
    unsigned short* __restrict__ Xb)
{
    for (int idx = blockIdx.x*256 + threadIdx.x; idx < 98400; idx += 192*256) {
        int r = idx / 96;
        __hip_bfloat16 hb = __float2bfloat16(dinv[r] * red[idx]);
        Xb[idx] = *(unsigned short*)&hb;
    }
}

// ---------------------------------------------------------------------------
// k_dec: R1-exact.
// ---------------------------------------------------------------------------
__global__ __launch_bounds__(256) void k_dec(
    const unsigned short* __restrict__ Xb,
    const float* __restrict__ cW, const float* __restrict__ cB,
    const float* __restrict__ lW, const float* __restrict__ lB,
    const float* __restrict__ bW, const float* __restrict__ bB,
    float* __restrict__ out)
{
    int b = blockIdx.x, tid = threadIdx.x;
    int w = tid >> 6, lane = tid & 63;
    int n16 = lane & 15, kg = lane >> 4;

    const float *W, *Bv;
    int g0, kcw, ncols, div, ostride;
    size_t obase;
    if (b < 576) {                       // conv decoder
        int kb = b >> 1, mb = b & 1;
        W = cW; Bv = cB; g0 = 1 + mb*256; kcw = kb*128 + w*32; ncols = 36864;
        div = 576; obase = (size_t)mb*256*36864; ostride = 36864;
    } else if (b < 608) {                // lin decoder
        int kb = b - 576;
        W = lW; Bv = lB; g0 = 513; kcw = kb*128 + w*32; ncols = 4096;
        div = 64; obase = (size_t)18874368; ostride = 4096;
    } else {                             // bias decoder
        W = bW; Bv = bB; g0 = 769; kcw = w*32; ncols = 64;
        div = 0; obase = (size_t)19922944; ostride = 64;
    }
    if (kcw >= ncols) return;

    int kc_a = kcw + n16, kc_b = kcw + 16 + n16;
    int row_a = div ? kc_a + (kc_a/div)*div : kc_a;   // padded row index
    int row_b = div ? kc_b + (kc_b/div)*div : kc_b;
    const float* Wa = W + (size_t)row_a*96 + kg*8;
    const float* Wb = W + (size_t)row_b*96 + kg*8;
    bf16x8 ba0 = cvt8(Wa);
    bf16x8 ba1 = cvt8(Wa + 32);
    bf16x8 ba2 = cvt8(Wa + 64);
    bf16x8 bb0 = cvt8(Wb);
    bf16x8 bb1 = cvt8(Wb + 32);
    bf16x8 bb2 = cvt8(Wb + 64);
    float bva = Bv[row_a], bvb = Bv[row_b];

#pragma unroll 2
    for (int mt = 0; mt < 16; ++mt) {
        const unsigned short* Ar = Xb + (size_t)(g0 + mt*16 + n16)*96 + kg*8;
        bf16x8 a0 = *(const bf16x8*)(Ar);
        bf16x8 a1 = *(const bf16x8*)(Ar + 32);
        bf16x8 a2 = *(const bf16x8*)(Ar + 64);
        f32x4 acc0 = {0.f,0.f,0.f,0.f}, acc1 = {0.f,0.f,0.f,0.f};
        acc0 = MFMA16(a0, ba0, acc0);
        acc0 = MFMA16(a1, ba1, acc0);
        acc0 = MFMA16(a2, ba2, acc0);
        acc1 = MFMA16(a0, bb0, acc1);
        acc1 = MFMA16(a1, bb1, acc1);
        acc1 = MFMA16(a2, bb2, acc1);
#pragma unroll
        for (int r = 0; r < 4; ++r) {
            int node = mt*16 + kg*4 + r;
            out[obase + (size_t)node*ostride + kc_a] = acc0[r] + bva;
            out[obase + (size_t)node*ostride + kc_b] = acc1[r] + bvb;
        }
    }
}

// ---------------------------------------------------------------------------
extern "C" void kernel_launch(void* const* d_in, const int* in_sizes, int n_in,
                              void* d_out, int out_size, void* d_ws, size_t ws_size,
                              hipStream_t stream)
{
    const float* conv_w     = (const float*)d_in[0];
    const float* lin_w      = (const float*)d_in[1];
    const float* bias_w     = (const float*)d_in[2];
    const float* conv_enc_w = (const float*)d_in[3];
    const float* conv_enc_b = (const float*)d_in[4];
    const float* lin_enc_w  = (const float*)d_in[5];
    const float* lin_enc_b  = (const float*)d_in[6];
    const float* bias_enc_w = (const float*)d_in[7];
    const float* bias_enc_b = (const float*)d_in[8];
    const float* gcn_w1     = (const float*)d_in[9];
    const float* gcn_w2     = (const float*)d_in[10];
    const float* conv_dec_w = (const float*)d_in[11];
    const float* conv_dec_b = (const float*)d_in[12];
    const float* lin_dec_w  = (const float*)d_in[13];
    const float* lin_dec_b  = (const float*)d_in[14];
    const float* bias_dec_w = (const float*)d_in[15];
    const float* bias_dec_b = (const float*)d_in[16];
    const float* embed_tab  = (const float*)d_in[17];
    const int*   adj        = (const int*)d_in[18];
    const int*   prims      = (const int*)d_in[19];

    // workspace (floats): P 16*1024*32 | Z1s | Z2s | dinv | Xb(bf16) | red
    float* P    = (float*)d_ws;             // 524288 f = 2 MB
    float* Z1s  = P + (size_t)16*1024*32;   // 98400 f
    float* Z2s  = Z1s + 1025*96;            // 98400 f
    float* dinv = Z2s + 1025*96;            // 1056 f
    unsigned short* Xb = (unsigned short*)(dinv + 1056);  // 98400 bf16
    float* red  = (float*)(Xb + (size_t)1025*96);         // 98400 f

    k_enc<<<656, 256, 0, stream>>>(conv_w, lin_w, bias_w,
                                   conv_enc_w, lin_enc_w, bias_enc_w,
                                   adj, P, dinv);
    k_z1<<<129, 256, 0, stream>>>(P, conv_enc_b, lin_enc_b, bias_enc_b,
                                  embed_tab, prims, gcn_w1, dinv, Z1s, red);
    k_propA<<<416, 256, 0, stream>>>(Z1s, adj, red);
    k_propF0<<<205, 256, 0, stream>>>(red, dinv, gcn_w2, Z2s, red);
    k_propA<<<416, 256, 0, stream>>>(Z2s, adj, red);
    k_propF1<<<192, 256, 0, stream>>>(red, dinv, Xb);
    k_dec<<<609, 256, 0, stream>>>(Xb, conv_dec_w, conv_dec_b,
                                   lin_dec_w, lin_dec_b,
                                   bias_dec_w, bias_dec_b,
                                   (float*)d_out);
}

// Round 6
// 299.291 us; speedup vs baseline: 1.7249x; 1.0149x over previous
//
#include <hip/hip_runtime.h>
#include <hip/hip_bf16.h>

// ---------------------------------------------------------------------------
// GHN (float32 I/O): encode (3 gathered GEMMs, bf16 MFMA, f32 acc)
//   -> 2-layer GCN -> decode (gathered GEMMs, MFMA) -> f32
// R6: k_enc restructured for B-reuse: 4 mtiles per block (B-slot traffic
// 151->38 MB; all prior variants were flat at ~47us with identical
// cache-side traffic -> redundant B streaming is the suspected binding
// resource). Block id = mg*16+ks pins each ks-slot's B to one XCD L2.
// k_z1/k_propA/k_propF0/k_propF1/k_dec identical to R5 (passed, 303.8us).
// ---------------------------------------------------------------------------

typedef __attribute__((ext_vector_type(8))) __bf16 bf16x8;
typedef __attribute__((ext_vector_type(4))) float f32x4;

#define MFMA16(a,b,c) __builtin_amdgcn_mfma_f32_16x16x32_bf16((a),(b),(c),0,0,0)

__device__ __forceinline__ bf16x8 cvt8(const float* p) {
    float4 a = *(const float4*)p;
    float4 b = *(const float4*)(p + 4);
    bf16x8 r;
    r[0]=(__bf16)a.x; r[1]=(__bf16)a.y; r[2]=(__bf16)a.z; r[3]=(__bf16)a.w;
    r[4]=(__bf16)b.x; r[5]=(__bf16)b.y; r[6]=(__bf16)b.z; r[7]=(__bf16)b.w;
    return r;
}

// single-mtile direct tile (bias encoder)
template<int KSTEPS, int DIV>
__device__ __forceinline__ void enc_tile(const float* Ar,
                                         const float* B0,
                                         const float* B1,
                                         int kw, int kg, f32x4& acc0, f32x4& acc1)
{
#pragma unroll
    for (int s = 0; s < KSTEPS; ++s) {
        int k = kw + s*32 + kg*8;
        int col = DIV ? (k + (k/DIV)*DIV) : k;
        bf16x8 a  = cvt8(Ar + k);
        bf16x8 b0 = cvt8(B0 + col);
        bf16x8 b1 = cvt8(B1 + col);
        acc0 = MFMA16(a, b0, acc0);
        acc1 = MFMA16(a, b1, acc1);
    }
}

// 4-mtile tile: one B load pair feeds 4 A tiles (8 MFMA) per K-step
template<int KSTEPS, int DIV>
__device__ __forceinline__ void enc_tile4(const float* Abase, size_t AST,
                                          const float* B0, const float* B1,
                                          int kw, int n16, int kg,
                                          f32x4 (&acc0)[4], f32x4 (&acc1)[4])
{
#pragma unroll
    for (int s = 0; s < KSTEPS; ++s) {
        int k = kw + s*32 + kg*8;
        int col = k + (k/DIV)*DIV;
        bf16x8 b0 = cvt8(B0 + col);
        bf16x8 b1 = cvt8(B1 + col);
#pragma unroll
        for (int m = 0; m < 4; ++m) {
            bf16x8 a = cvt8(Abase + (size_t)(m*16 + n16)*AST + k);
            acc0[m] = MFMA16(a, b0, acc0[m]);
            acc1[m] = MFMA16(a, b1, acc1[m]);
        }
    }
}

// ---------------------------------------------------------------------------
// k_enc: conv 128 blocks (8 mg x 16 ks, id=mg*16+ks), lin 16, bias 16,
// dinv 64. 256 thr / 4 waves. LDS reduce: R[wave][m][16x32] = 32 KB.
// ---------------------------------------------------------------------------
__global__ __launch_bounds__(256) void k_enc(
    const float* __restrict__ conv_w,
    const float* __restrict__ lin_w,
    const float* __restrict__ bias_w,
    const float* __restrict__ conv_enc_w,
    const float* __restrict__ lin_enc_w,
    const float* __restrict__ bias_enc_w,
    const int* __restrict__ adj,
    float* __restrict__ P, float* __restrict__ dinv)
{
    int b = blockIdx.x, tid = threadIdx.x;
    int w = tid >> 6, lane = tid & 63;
    int n16 = lane & 15, kg = lane >> 4;

    if (b >= 160) {  // ---- dinv rows (64 blocks, R1-exact math)
        int wid = (b - 160)*4 + w;
        for (int r = wid; r < 1025; r += 256) {
            const int* row = adj + (size_t)r*1025;
            int s = 0;
#pragma unroll
            for (int i = 0; i <= 16; ++i) {
                int j = lane + i*64;
                if (j < 1025) s += row[j];
            }
#pragma unroll
            for (int off = 32; off; off >>= 1) s += __shfl_xor(s, off, 64);
            if (lane == 0) dinv[r] = 1.0f / sqrtf((float)s + 1.0f);
        }
        return;
    }

    __shared__ float R[4*4*512];   // 32 KB: [wave][mtile][(kg*4+r)*32+col]

    if (b < 144) {   // ---- conv (b<128) & lin (128<=b<144): 4-mtile path
        f32x4 acc0[4] = {{0,0,0,0},{0,0,0,0},{0,0,0,0},{0,0,0,0}};
        f32x4 acc1[4] = {{0,0,0,0},{0,0,0,0},{0,0,0,0},{0,0,0,0}};
        int slot, nodebase, mbase;
        if (b < 128) {            // conv: M=512, K=36864; mg=b>>4, ks=b&15
            int mg = b >> 4, ks = b & 15;
            slot = ks; nodebase = 0; mbase = mg*4;
            const float* B0 = conv_enc_w + (size_t)n16*147456;
            const float* B1 = conv_enc_w + (size_t)(16+n16)*147456;
            enc_tile4<18,576>(conv_w + (size_t)mbase*16*36864, 36864,
                              B0, B1, ks*2304 + w*576, n16, kg, acc0, acc1);
        } else {                  // lin: M=256, K=4096; 4 mg x 4 ks
            int bb = b - 128; int mg = bb >> 2, ks = bb & 3;
            slot = ks; nodebase = 512; mbase = mg*4;
            const float* B0 = lin_enc_w + (size_t)n16*16384;
            const float* B1 = lin_enc_w + (size_t)(16+n16)*16384;
            enc_tile4<8,64>(lin_w + (size_t)mbase*16*4096, 4096,
                            B0, B1, ks*1024 + w*256, n16, kg, acc0, acc1);
        }
#pragma unroll
        for (int m = 0; m < 4; ++m)
#pragma unroll
            for (int r = 0; r < 4; ++r) {
                R[((w*4 + m)*16 + kg*4 + r)*32 + n16]      = acc0[m][r];
                R[((w*4 + m)*16 + kg*4 + r)*32 + 16 + n16] = acc1[m][r];
            }
        __syncthreads();
        for (int e = tid; e < 2048; e += 256) {
            int m = e >> 9, wi = e & 511;
            float s = R[m*512 + wi]        + R[(4+m)*512 + wi]
                    + R[(8+m)*512 + wi]    + R[(12+m)*512 + wi];
            int nl = wi >> 5, h = wi & 31;
            int node = nodebase + (mbase + m)*16 + nl;
            P[((size_t)slot*1024 + node)*32 + h] = s;
        }
    } else {         // ---- bias (144<=b<160): single-mtile R1 path
        int mtile = b - 144;
        f32x4 acc0 = {0,0,0,0}, acc1 = {0,0,0,0};
        if (w < 2) {
            const float* Ar = bias_w     + (size_t)(mtile*16 + n16)*64;
            const float* B0 = bias_enc_w + (size_t)n16*128;
            const float* B1 = bias_enc_w + (size_t)(16+n16)*128;
            enc_tile<1,0>(Ar, B0, B1, w*32, kg, acc0, acc1);
        }
#pragma unroll
        for (int r = 0; r < 4; ++r) {
            R[(w*16 + kg*4 + r)*32 + n16]      = acc0[r];
            R[(w*16 + kg*4 + r)*32 + 16 + n16] = acc1[r];
        }
        __syncthreads();
        for (int e = tid; e < 512; e += 256) {
            float s = R[e] + R[512+e] + R[1024+e] + R[1536+e];
            int nl = e >> 5, h = e & 31;
            int node = 768 + mtile*16 + nl;
            P[(size_t)node*32 + h] = s;          // slot 0
        }
    }
}

// ---------------------------------------------------------------------------
// k_z1: R5-exact (+ red zeroing)
// ---------------------------------------------------------------------------
__global__ __launch_bounds__(256) void k_z1(
    const float* __restrict__ P,
    const float* __restrict__ conv_enc_b,
    const float* __restrict__ lin_enc_b,
    const float* __restrict__ bias_enc_b,
    const float* __restrict__ embed_tab,
    const int* __restrict__ prims,
    const float* __restrict__ gcn_w1,
    const float* __restrict__ dinv,
    float* __restrict__ Z1s,
    float* __restrict__ red)
{
    __shared__ float El[8*32], Ml[8*32];
    int tid = threadIdx.x;
    int i0 = blockIdx.x * 8;

    for (int idx = blockIdx.x*256 + tid; idx < 98400; idx += 129*256)
        red[idx] = 0.f;

    {
        int rl = tid >> 5, h = tid & 31;
        int i = i0 + rl;
        if (i < 1025) {
            float e, m;
            if (i == 0) { e = 1.0f; m = 1.0f; }
            else {
                int node = i - 1;
                int ns; float bias;
                if (node < 512)      { ns = 16; bias = conv_enc_b[h]; }
                else if (node < 768) { ns = 4;  bias = lin_enc_b[h];  }
                else                 { ns = 1;  bias = bias_enc_b[h]; }
                float s = bias;
                for (int sl = 0; sl < ns; ++sl)
                    s += P[((size_t)sl*1024 + node)*32 + h];
                e = s;
                m = embed_tab[prims[node]*32 + h];
            }
            El[rl*32+h] = e; Ml[rl*32+h] = m;
        }
    }
    __syncthreads();
    if (tid < 192) {
        int rl = tid / 24, c4 = tid % 24;
        int i = i0 + rl;
        if (i < 1025) {
            float a0=0,a1=0,a2=0,a3=0;
            for (int h = 0; h < 32; ++h) {
                float e = El[rl*32+h], m = Ml[rl*32+h];
                float4 wa = *(const float4*)(gcn_w1 + h*96 + c4*4);
                float4 wb = *(const float4*)(gcn_w1 + (h+32)*96 + c4*4);
                float4 wc = *(const float4*)(gcn_w1 + (h+64)*96 + c4*4);
                a0 += e*(wa.x+wb.x) + m*wc.x;
                a1 += e*(wa.y+wb.y) + m*wc.y;
                a2 += e*(wa.z+wb.z) + m*wc.z;
                a3 += e*(wa.w+wb.w) + m*wc.w;
            }
            float di = dinv[i];
            float* o = Z1s + (size_t)i*96 + c4*4;
            o[0] = di*a0; o[1] = di*a1; o[2] = di*a2; o[3] = di*a3;
        }
    }
}

// ---------------------------------------------------------------------------
// k_propA: R5-exact
// ---------------------------------------------------------------------------
__global__ __launch_bounds__(256) void k_propA(
    const float* __restrict__ Zs, const int* __restrict__ adj,
    float* __restrict__ red)
{
    __shared__ float adjf[20*132];
    int tid = threadIdx.x;
    int jc = blockIdx.x & 7, it = blockIdx.x >> 3;
    int i0 = it * 20;
    int j0 = jc * 128;
    int jlen = (jc == 7) ? 129 : 128;

    for (int idx = tid; idx < 20*132; idx += 256) {
        int row = idx / 132, c = idx % 132;
        int i = i0 + row, j = j0 + c;
        if (c < jlen && i < 1025)
            adjf[row*132 + c] = (float)adj[(size_t)i*1025 + j]
                                + (i == j ? 1.0f : 0.0f);
    }
    __syncthreads();

    if (tid < 240) {
        int c4 = tid % 24, ig = tid / 24;
        int rA = i0 + ig, rB = i0 + ig + 10;
        float accA[4] = {0,0,0,0}, accB[4] = {0,0,0,0};
        for (int jj = 0; jj < jlen; ++jj) {
            const float4 z = *(const float4*)(Zs + (size_t)(j0+jj)*96 + c4*4);
            float aA = adjf[ig*132 + jj];
            float aB = adjf[(ig+10)*132 + jj];
            accA[0] += aA*z.x; accA[1] += aA*z.y;
            accA[2] += aA*z.z; accA[3] += aA*z.w;
            accB[0] += aB*z.x; accB[1] += aB*z.y;
            accB[2] += aB*z.z; accB[3] += aB*z.w;
        }
        if (rA < 1025) {
            float* o = red + (size_t)rA*96 + c4*4;
            atomicAdd(o+0, accA[0]); atomicAdd(o+1, accA[1]);
            atomicAdd(o+2, accA[2]); atomicAdd(o+3, accA[3]);
        }
        if (rB < 1025) {
            float* o = red + (size_t)rB*96 + c4*4;
            atomicAdd(o+0, accB[0]); atomicAdd(o+1, accB[1]);
            atomicAdd(o+2, accB[2]); atomicAdd(o+3, accB[3]);
        }
    }
}

// ---------------------------------------------------------------------------
// k_propF0: R5-exact
// ---------------------------------------------------------------------------
__global__ __launch_bounds__(256) void k_propF0(
    const float* __restrict__ red, const float* __restrict__ dinv,
    const float* __restrict__ gcn_w2,
    float* __restrict__ Z2s, float* __restrict__ redz)
{
    __shared__ float redl[5*96];
    int tid = threadIdx.x;
    int i0 = blockIdx.x * 5;
    for (int idx = tid; idx < 5*96; idx += 256) {
        int r = idx / 96, c = idx % 96;
        int i = i0 + r;
        if (i < 1025) {
            redl[idx] = red[(size_t)i*96 + c];
            redz[(size_t)i*96 + c] = 0.f;
        }
    }
    __syncthreads();
    if (tid < 120) {
        int c4 = tid % 24, ig = tid / 24;
        int i = i0 + ig;
        if (i < 1025) {
            float di = dinv[i];
            float o0=0,o1=0,o2=0,o3=0;
            for (int c = 0; c < 96; ++c) {
                float hv = redl[ig*96 + c] * di; hv = hv > 0.f ? hv : 0.f;
                float4 w2 = *(const float4*)(gcn_w2 + c*96 + c4*4);
                o0 += hv*w2.x; o1 += hv*w2.y; o2 += hv*w2.z; o3 += hv*w2.w;
            }
            float* o = Z2s + (size_t)i*96 + c4*4;
            o[0] = di*o0; o[1] = di*o1; o[2] = di*o2; o[3] = di*o3;
        }
    }
}

// ---------------------------------------------------------------------------
// k_propF1: R5-exact
// ---------------------------------------------------------------------------
__global__ __launch_bounds__(256) void k_propF1(
    const float* __restrict__ red, const float* __restrict__ dinv,
    unsigned short* __restrict__ Xb)
{
    for (int idx = blockIdx.x*256 + threadIdx.x; idx < 98400; idx += 192*256) {
        int r = idx / 96;
        __hip_bfloat16 hb = __float2bfloat16(dinv[r] * red[idx]);
        Xb[idx] = *(unsigned short*)&hb;
    }
}

// ---------------------------------------------------------------------------
// k_dec: R5-exact
// ---------------------------------------------------------------------------
__global__ __launch_bounds__(256) void k_dec(
    const unsigned short* __restrict__ Xb,
    const float* __restrict__ cW, const float* __restrict__ cB,
    const float* __restrict__ lW, const float* __restrict__ lB,
    const float* __restrict__ bW, const float* __restrict__ bB,
    float* __restrict__ out)
{
    int b = blockIdx.x, tid = threadIdx.x;
    int w = tid >> 6, lane = tid & 63;
    int n16 = lane & 15, kg = lane >> 4;

    const float *W, *Bv;
    int g0, kcw, ncols, div, ostride;
    size_t obase;
    if (b < 576) {                       // conv decoder
        int kb = b >> 1, mb = b & 1;
        W = cW; Bv = cB; g0 = 1 + mb*256; kcw = kb*128 + w*32; ncols = 36864;
        div = 576; obase = (size_t)mb*256*36864; ostride = 36864;
    } else if (b < 608) {                // lin decoder
        int kb = b - 576;
        W = lW; Bv = lB; g0 = 513; kcw = kb*128 + w*32; ncols = 4096;
        div = 64; obase = (size_t)18874368; ostride = 4096;
    } else {                             // bias decoder
        W = bW; Bv = bB; g0 = 769; kcw = w*32; ncols = 64;
        div = 0; obase = (size_t)19922944; ostride = 64;
    }
    if (kcw >= ncols) return;

    int kc_a = kcw + n16, kc_b = kcw + 16 + n16;
    int row_a = div ? kc_a + (kc_a/div)*div : kc_a;
    int row_b = div ? kc_b + (kc_b/div)*div : kc_b;
    const float* Wa = W + (size_t)row_a*96 + kg*8;
    const float* Wb = W + (size_t)row_b*96 + kg*8;
    bf16x8 ba0 = cvt8(Wa);
    bf16x8 ba1 = cvt8(Wa + 32);
    bf16x8 ba2 = cvt8(Wa + 64);
    bf16x8 bb0 = cvt8(Wb);
    bf16x8 bb1 = cvt8(Wb + 32);
    bf16x8 bb2 = cvt8(Wb + 64);
    float bva = Bv[row_a], bvb = Bv[row_b];

#pragma unroll 2
    for (int mt = 0; mt < 16; ++mt) {
        const unsigned short* Ar = Xb + (size_t)(g0 + mt*16 + n16)*96 + kg*8;
        bf16x8 a0 = *(const bf16x8*)(Ar);
        bf16x8 a1 = *(const bf16x8*)(Ar + 32);
        bf16x8 a2 = *(const bf16x8*)(Ar + 64);
        f32x4 acc0 = {0.f,0.f,0.f,0.f}, acc1 = {0.f,0.f,0.f,0.f};
        acc0 = MFMA16(a0, ba0, acc0);
        acc0 = MFMA16(a1, ba1, acc0);
        acc0 = MFMA16(a2, ba2, acc0);
        acc1 = MFMA16(a0, bb0, acc1);
        acc1 = MFMA16(a1, bb1, acc1);
        acc1 = MFMA16(a2, bb2, acc1);
#pragma unroll
        for (int r = 0; r < 4; ++r) {
            int node = mt*16 + kg*4 + r;
            out[obase + (size_t)node*ostride + kc_a] = acc0[r] + bva;
            out[obase + (size_t)node*ostride + kc_b] = acc1[r] + bvb;
        }
    }
}

// ---------------------------------------------------------------------------
extern "C" void kernel_launch(void* const* d_in, const int* in_sizes, int n_in,
                              void* d_out, int out_size, void* d_ws, size_t ws_size,
                              hipStream_t stream)
{
    const float* conv_w     = (const float*)d_in[0];
    const float* lin_w      = (const float*)d_in[1];
    const float* bias_w     = (const float*)d_in[2];
    const float* conv_enc_w = (const float*)d_in[3];
    const float* conv_enc_b = (const float*)d_in[4];
    const float* lin_enc_w  = (const float*)d_in[5];
    const float* lin_enc_b  = (const float*)d_in[6];
    const float* bias_enc_w = (const float*)d_in[7];
    const float* bias_enc_b = (const float*)d_in[8];
    const float* gcn_w1     = (const float*)d_in[9];
    const float* gcn_w2     = (const float*)d_in[10];
    const float* conv_dec_w = (const float*)d_in[11];
    const float* conv_dec_b = (const float*)d_in[12];
    const float* lin_dec_w  = (const float*)d_in[13];
    const float* lin_dec_b  = (const float*)d_in[14];
    const float* bias_dec_w = (const float*)d_in[15];
    const float* bias_dec_b = (const float*)d_in[16];
    const float* embed_tab  = (const float*)d_in[17];
    const int*   adj        = (const int*)d_in[18];
    const int*   prims      = (const int*)d_in[19];

    // workspace (floats): P 16*1024*32 | Z1s | Z2s | dinv | Xb(bf16) | red
    float* P    = (float*)d_ws;             // 524288 f = 2 MB
    float* Z1s  = P + (size_t)16*1024*32;   // 98400 f
    float* Z2s  = Z1s + 1025*96;            // 98400 f
    float* dinv = Z2s + 1025*96;            // 1056 f
    unsigned short* Xb = (unsigned short*)(dinv + 1056);  // 98400 bf16
    float* red  = (float*)(Xb + (size_t)1025*96);         // 98400 f

    k_enc<<<224, 256, 0, stream>>>(conv_w, lin_w, bias_w,
                                   conv_enc_w, lin_enc_w, bias_enc_w,
                                   adj, P, dinv);
    k_z1<<<129, 256, 0, stream>>>(P, conv_enc_b, lin_enc_b, bias_enc_b,
                                  embed_tab, prims, gcn_w1, dinv, Z1s, red);
    k_propA<<<416, 256, 0, stream>>>(Z1s, adj, red);
    k_propF0<<<205, 256, 0, stream>>>(red, dinv, gcn_w2, Z2s, red);
    k_propA<<<416, 256, 0, stream>>>(Z2s, adj, red);
    k_propF1<<<192, 256, 0, stream>>>(red, dinv, Xb);
    k_dec<<<609, 256, 0, stream>>>(Xb, conv_dec_w, conv_dec_b,
                                   lin_dec_w, lin_dec_b,
                                   bias_dec_w, bias_dec_b,
                                   (float*)d_out);
}